// Round 4
// baseline (537.342 us; speedup 1.0000x reference)
//
#include <hip/hip_runtime.h>
#include <stdint.h>

constexpr int B = 4;
constexpr int N = 262144;
constexpr int C = 10;
constexpr int KPRE = 4096;
constexpr int KPOST = 500;
constexpr float ROI_THR = 0.1f;
constexpr float NMS_THR = 0.01f;
constexpr int CAP = 8192;        // compaction capacity (>= KPRE + boundary-bin ties)
constexpr int MASKW = KPRE / 64; // 64 u64 words per mask row

__device__ __forceinline__ uint32_t f2k(float f) {
  uint32_t u = __float_as_uint(f);
  return (u & 0x80000000u) ? ~u : (u | 0x80000000u);
}
__device__ __forceinline__ float k2f(uint32_t k) {
  uint32_t u = (k & 0x80000000u) ? (k ^ 0x80000000u) : ~k;
  return __uint_as_float(u);
}
__device__ __forceinline__ float sigm(float x) { return 1.0f / (1.0f + expf(-x)); }

__device__ __forceinline__ void async_lds16(const void* g, void* l) {
  __builtin_amdgcn_global_load_lds((const __attribute__((address_space(1))) void*)g,
                                   (__attribute__((address_space(3))) void*)l, 16, 0, 0);
}

// ---------------- K0: scores -> sortable keys + 16-bit-prefix histogram ----------------
__global__ void scoreK(const float* __restrict__ cls, uint32_t* __restrict__ keys,
                       uint32_t* __restrict__ fine) {
  int n = blockIdx.x * blockDim.x + threadIdx.x;
  int b = blockIdx.y;
  if (n >= N) return;
  const float2* pp = (const float2*)(cls + ((size_t)b * N + n) * C);
  float2 v0 = pp[0], v1 = pp[1], v2 = pp[2], v3 = pp[3], v4 = pp[4];
  float m = sigm(v0.x);
  m = fmaxf(m, sigm(v0.y));
  m = fmaxf(m, sigm(v1.x));
  m = fmaxf(m, sigm(v1.y));
  m = fmaxf(m, sigm(v2.x));
  m = fmaxf(m, sigm(v2.y));
  m = fmaxf(m, sigm(v3.x));
  m = fmaxf(m, sigm(v3.y));
  m = fmaxf(m, sigm(v4.x));
  m = fmaxf(m, sigm(v4.y));
  float s = (m > ROI_THR) ? m : -1.0f;
  uint32_t k = f2k(s);
  keys[(size_t)b * N + n] = k;
  atomicAdd(&fine[(size_t)b * 65536 + (k >> 16)], 1u);
}

// ---------------- K1: two-level scan over 64K-bin histogram -> threshold T[b] ----------------
__device__ __forceinline__ void suffix_scan256(uint32_t* s, int t) {
  for (int off = 1; off < 256; off <<= 1) {
    uint32_t v = s[t] + ((t + off < 256) ? s[t + off] : 0u);
    __syncthreads();
    s[t] = v;
    __syncthreads();
  }
}
__global__ void scan16K(const uint32_t* __restrict__ fine, uint32_t* __restrict__ T) {
  __shared__ uint32_t s[256];
  __shared__ uint32_t sel_sh[2];
  int b = blockIdx.x;
  int t = threadIdx.x;
  const uint32_t* fb = fine + (size_t)b * 65536;
  // coarse sums: thread t = sum of fine bins [t*256, t*256+256)
  uint32_t acc = 0;
  const uint32_t* chunk = fb + t * 256;
#pragma unroll 8
  for (int k = 0; k < 256; ++k) acc += chunk[k];
  s[t] = acc;
  __syncthreads();
  suffix_scan256(s, t); // s[t] = sum over coarse bins >= t
  uint32_t suf = s[t];
  uint32_t sufn = (t < 255) ? s[t + 1] : 0u;
  if (suf >= (uint32_t)KPRE && sufn < (uint32_t)KPRE) {
    sel_sh[0] = (uint32_t)t;
    sel_sh[1] = (uint32_t)KPRE - sufn; // residual rank within coarse bin
  }
  __syncthreads();
  uint32_t cb = sel_sh[0], R1 = sel_sh[1];
  uint32_t f = fb[cb * 256 + t];
  __syncthreads();
  s[t] = f;
  __syncthreads();
  suffix_scan256(s, t);
  suf = s[t];
  sufn = (t < 255) ? s[t + 1] : 0u;
  if (suf >= R1 && sufn < R1) sel_sh[0] = (cb << 8) | (uint32_t)t;
  __syncthreads();
  if (t == 0) T[b] = sel_sh[0] << 16;
}

// ---------------- K2: compact all keys >= T ----------------
__global__ void compactK(const uint32_t* __restrict__ keys, const uint32_t* __restrict__ T,
                         unsigned long long* __restrict__ list, uint32_t* __restrict__ cnt) {
  int b = blockIdx.y;
  uint32_t Tb = T[b];
  const uint32_t* kb = keys + (size_t)b * N;
  for (int n = blockIdx.x * blockDim.x + threadIdx.x; n < N; n += gridDim.x * blockDim.x) {
    uint32_t k = kb[n];
    if (k >= Tb) {
      uint32_t pos = atomicAdd(&cnt[b], 1u);
      if (pos < CAP)
        list[(size_t)b * CAP + pos] = ((unsigned long long)k << 32) | (uint32_t)(~(uint32_t)n);
    }
  }
}

// ---------------- K3: exact rank by counting (desc by pack = key desc, idx asc) ----------------
__global__ void rankK(const unsigned long long* __restrict__ list, const uint32_t* __restrict__ cnt,
                      uint32_t* __restrict__ rank) {
  __shared__ unsigned long long lp[256];
  int b = blockIdx.z;
  int cc = (int)min(cnt[b], (uint32_t)CAP);
  if (blockIdx.x * 256 >= cc || blockIdx.y * 256 >= cc) return; // block-uniform
  int i = blockIdx.x * 256 + threadIdx.x;
  int j = blockIdx.y * 256 + threadIdx.x;
  lp[threadIdx.x] = (j < cc) ? list[(size_t)b * CAP + j] : 0ull;
  bool vi = (i < cc);
  unsigned long long pi = vi ? list[(size_t)b * CAP + i] : ~0ull;
  __syncthreads();
  if (!vi) return;
  uint32_t c = 0;
#pragma unroll 8
  for (int jj = 0; jj < 256; ++jj) c += (lp[jj] > pi) ? 1u : 0u;
  if (c) atomicAdd(&rank[(size_t)b * CAP + i], c);
}

// ---------------- K4: scatter item -> position rank; gather boxes ----------------
__global__ void scatterK(const unsigned long long* __restrict__ list,
                         const uint32_t* __restrict__ cnt, const uint32_t* __restrict__ rank,
                         const float* __restrict__ boxes, float* __restrict__ sel_score,
                         uint32_t* __restrict__ sel_idx, float* __restrict__ sel_box) {
  int b = blockIdx.y;
  int p = blockIdx.x * 256 + threadIdx.x;
  uint32_t cc = min(cnt[b], (uint32_t)CAP);
  if (p >= (int)cc) return;
  unsigned long long pk = list[(size_t)b * CAP + p];
  uint32_t r = rank[(size_t)b * CAP + p];
  if (r >= (uint32_t)KPRE) return;
  uint32_t key = (uint32_t)(pk >> 32);
  uint32_t idx = ~(uint32_t)pk;
  sel_score[b * KPRE + r] = k2f(key);
  sel_idx[b * KPRE + r] = idx;
  const float* src = boxes + ((size_t)b * N + idx) * 7;
  float* dst = sel_box + ((size_t)b * KPRE + r) * 8;
#pragma unroll
  for (int c = 0; c < 7; ++c) dst[c] = src[c];
  dst[7] = 0.f;
}

// ---------------- K5: pairwise IoU suppression bitmask (2D tiled) ----------------
__global__ void maskK(const float* __restrict__ sel_box, unsigned long long* __restrict__ mask) {
  int b = blockIdx.z;
  int bi = blockIdx.x;
  int w = blockIdx.y;
  int t = threadIdx.x;
  int i = bi * 256 + t;
  int j0 = w * 64;
  unsigned long long* dst = mask + ((size_t)b * KPRE + i) * MASKW + w;
  if (j0 + 63 <= bi * 256) { // whole tile is j <= i: no suppression bits
    *dst = 0ull;
    return;
  }
  __shared__ float jx1[64], jx2[64], jy1[64], jy2[64], ja[64];
  if (t < 64) {
    const float4* bj = (const float4*)(sel_box + ((size_t)b * KPRE + j0 + t) * 8);
    float4 lo = bj[0], hi = bj[1];
    float xj = lo.x, yj = lo.y, dxj = lo.w, dyj = hi.x;
    float hxj = __fmul_rn(dxj, 0.5f), hyj = __fmul_rn(dyj, 0.5f);
    jx1[t] = __fsub_rn(xj, hxj);
    jx2[t] = __fadd_rn(xj, hxj);
    jy1[t] = __fsub_rn(yj, hyj);
    jy2[t] = __fadd_rn(yj, hyj);
    ja[t] = __fmul_rn(dxj, dyj);
  }
  __syncthreads();
  const float4* myb = (const float4*)(sel_box + ((size_t)b * KPRE + i) * 8);
  float4 lo = myb[0], hi = myb[1];
  float x = lo.x, y = lo.y, dx = lo.w, dy = hi.x;
  float hx = __fmul_rn(dx, 0.5f), hy = __fmul_rn(dy, 0.5f);
  float x1i = __fsub_rn(x, hx), x2i = __fadd_rn(x, hx);
  float y1i = __fsub_rn(y, hy), y2i = __fadd_rn(y, hy);
  float ai = __fmul_rn(dx, dy);
  unsigned long long wacc = 0ull;
#pragma unroll 16
  for (int jj = 0; jj < 64; ++jj) {
    int j = j0 + jj;
    float xx1 = fmaxf(x1i, jx1[jj]);
    float xx2 = fminf(x2i, jx2[jj]);
    float yy1 = fmaxf(y1i, jy1[jj]);
    float yy2 = fminf(y2i, jy2[jj]);
    float ix = fmaxf(__fsub_rn(xx2, xx1), 0.0f);
    float iy = fmaxf(__fsub_rn(yy2, yy1), 0.0f);
    float inter = __fmul_rn(ix, iy);
    float uni = __fsub_rn(__fadd_rn(ai, ja[jj]), inter);
    float iou = inter / fmaxf(uni, 1e-6f);
    bool sup = (iou > NMS_THR) && (j > i);
    wacc |= ((unsigned long long)(sup ? 1u : 0u)) << jj;
  }
  *dst = wacc;
}

// ---------------- K6: greedy NMS scan, group-parallel (1 wave / batch) ----------------
// Per 64-item group g: lane t's kill-word m = lds[t][g]. Resolve via ballot chain; the
// "does s kill me" test is a wave-uniform broadcast LDS read lds[s][g] (no transpose).
// Row-OR of kept items iterates only set bits of alive. Rows double-buffer-prefetched
// one group ahead via global_load_lds.
__global__ void nmsK(const unsigned long long* __restrict__ mask,
                     const float* __restrict__ sel_score,
                     uint32_t* __restrict__ kept_pos, uint32_t* __restrict__ kept_cnt) {
  __shared__ unsigned long long lds[2][64][64]; // 64 KiB double buffer
  int b = blockIdx.x;
  int t = threadIdx.x; // lane 0..63; owns remv word t

  unsigned long long cand = 0ull;
  for (int k = 0; k < 64; ++k) {
    float s = sel_score[b * KPRE + k * 64 + t];
    unsigned long long bal = __ballot(s > ROI_THR);
    if (t == k) cand = bal;
  }

  const unsigned long long* mb = mask + (size_t)b * KPRE * MASKW;
  unsigned long long remv = 0ull;
  int kc = 0;

  auto prefetch = [&](int g, int buf2) {
    const char* base = (const char*)(mb + (size_t)g * 64 * MASKW);
#pragma unroll
    for (int p = 0; p < 32; ++p)
      async_lds16(base + (size_t)p * 1024 + (size_t)t * 16, &lds[buf2][p * 2][0]);
  };

  prefetch(0, 0);
  for (int g = 0; g < 64; ++g) {
    int buf = g & 1;
    asm volatile("s_waitcnt vmcnt(0)" ::: "memory"); // current buf ready
    if (g + 1 < 64) prefetch(g + 1, buf ^ 1);        // overlap next with processing

    unsigned long long cw = cand & ~remv;
    unsigned long long aw = (unsigned long long)__shfl((long long)cw, g, 64);
    if (aw) {
      unsigned long long m = lds[buf][t][g]; // who I kill within group (bits > t)
      unsigned long long K = __ballot((m & aw) != 0ull);
      unsigned long long alive = aw;
      unsigned long long rem = aw & K;
      if (rem) {
        bool deadf = ((aw >> t) & 1ull) == 0ull;
        while (rem) {
          int s = __ffsll((long long)rem) - 1;
          rem &= rem - 1ull;
          if ((alive >> s) & 1ull) { // s is final-alive here (ascending order)
            unsigned long long row_s = lds[buf][s][g]; // broadcast read
            deadf = deadf || (((row_s >> t) & 1ull) != 0ull);
            alive = __ballot(!deadf);
            rem &= alive;
          }
        }
      }
      int grp = __popcll(alive);
      if ((alive >> t) & 1ull) {
        int rk = __popcll(alive & ((1ull << t) - 1ull));
        if (kc + rk < KPOST) kept_pos[b * KPOST + kc + rk] = g * 64 + t;
      }
      unsigned long long acc = 0ull, a2 = alive;
      while (a2) {
        int s2 = __ffsll((long long)a2) - 1;
        a2 &= a2 - 1ull;
        acc |= lds[buf][s2][t];
      }
      remv |= acc;
      kc += grp;
      if (kc >= KPOST) break;
    }
  }
  asm volatile("s_waitcnt vmcnt(0)" ::: "memory"); // drain in-flight prefetch
  if (t == 0) kept_cnt[b] = (uint32_t)min(kc, KPOST);
}

// ---------------- K7: emit outputs ----------------
__global__ void outK(const float* __restrict__ cls,
                     const float* __restrict__ sel_score, const uint32_t* __restrict__ sel_idx,
                     const float* __restrict__ sel_box,
                     const uint32_t* __restrict__ kept_pos, const uint32_t* __restrict__ kept_cnt,
                     float* __restrict__ out) {
  int b = blockIdx.y;
  int s = blockIdx.x * blockDim.x + threadIdx.x;
  if (s >= KPOST) return;
  float* oS = out;                             // (B, KPOST)
  float* oB = out + B * KPOST;                 // (B, KPOST, 7)
  float* oL = out + B * KPOST + B * KPOST * 7; // (B, KPOST)
  uint32_t kcnt = kept_cnt[b];
  if (s < (int)kcnt) {
    uint32_t pos = kept_pos[b * KPOST + s];
    oS[b * KPOST + s] = sel_score[b * KPRE + pos];
    const float* box = sel_box + ((size_t)b * KPRE + pos) * 8;
    float* dst = oB + ((size_t)b * KPOST + s) * 7;
#pragma unroll
    for (int c = 0; c < 7; ++c) dst[c] = box[c];
    uint32_t idx = sel_idx[b * KPRE + pos];
    const float* p = cls + ((size_t)b * N + idx) * C;
    float bestv = sigm(p[0]);
    int bestc = 0;
#pragma unroll
    for (int c = 1; c < C; ++c) {
      float v = sigm(p[c]);
      if (v > bestv) { bestv = v; bestc = c; }
    }
    oL[b * KPOST + s] = (float)bestc;
  } else {
    oS[b * KPOST + s] = 0.0f;
    float* dst = oB + ((size_t)b * KPOST + s) * 7;
#pragma unroll
    for (int c = 0; c < 7; ++c) dst[c] = 0.0f;
    oL[b * KPOST + s] = -1.0f;
  }
}

__global__ void sentinelK(float* out, int n) {
  int i = blockIdx.x * blockDim.x + threadIdx.x;
  if (i < n) out[i] = 1337.0f;
}

extern "C" void kernel_launch(void* const* d_in, const int* in_sizes, int n_in,
                              void* d_out, int out_size, void* d_ws, size_t ws_size,
                              hipStream_t stream) {
  const float* cls = (const float*)d_in[0];
  const float* boxes = (const float*)d_in[1];
  float* out = (float*)d_out;

  char* ws = (char*)d_ws;
  size_t off = 0;
  auto alloc = [&](size_t bytes) -> void* {
    void* p = ws + off;
    off = (off + bytes + 255) & ~(size_t)255;
    return p;
  };
  unsigned long long* mask = (unsigned long long*)alloc((size_t)B * KPRE * MASKW * 8); // 8 MB
  unsigned long long* list = (unsigned long long*)alloc((size_t)B * CAP * 8);
  uint32_t* keys = (uint32_t*)alloc((size_t)B * N * 4);
  float* sel_box = (float*)alloc((size_t)B * KPRE * 8 * 4);
  float* sel_score = (float*)alloc((size_t)B * KPRE * 4);
  uint32_t* sel_idx = (uint32_t*)alloc((size_t)B * KPRE * 4);
  uint32_t* kept_pos = (uint32_t*)alloc((size_t)B * KPOST * 4);
  uint32_t* Tbuf = (uint32_t*)alloc(B * 4);

  // fine-hist / rank / cnt / kept_cnt alias the mask region: all are dead before maskK
  // writes mask, and kept_cnt is rewritten unconditionally by nmsK (after maskK).
  uint32_t* fine = (uint32_t*)mask;                                   // B*64K u32 = 1 MB
  uint32_t* rank = (uint32_t*)((char*)mask + (size_t)B * 65536 * 4);  // B*CAP u32 = 128 KB
  uint32_t* cnt = (uint32_t*)((char*)rank + (size_t)B * CAP * 4);     // B u32
  uint32_t* kept_cnt = cnt + 64;                                      // B u32
  size_t zbytes = (size_t)B * 65536 * 4 + (size_t)B * CAP * 4 + 512;

  if (off > ws_size) {
    sentinelK<<<dim3((out_size + 255) / 256), 256, 0, stream>>>(out, out_size);
    return;
  }

  hipMemsetAsync(mask, 0, zbytes, stream);
  scoreK<<<dim3(N / 256, B), 256, 0, stream>>>(cls, keys, fine);
  scan16K<<<B, 256, 0, stream>>>(fine, Tbuf);
  compactK<<<dim3(256, B), 256, 0, stream>>>(keys, Tbuf, list, cnt);
  rankK<<<dim3(CAP / 256, CAP / 256, B), 256, 0, stream>>>(list, cnt, rank);
  scatterK<<<dim3(CAP / 256, B), 256, 0, stream>>>(list, cnt, rank, boxes, sel_score, sel_idx,
                                                   sel_box);
  maskK<<<dim3(16, 64, B), 256, 0, stream>>>(sel_box, mask);
  nmsK<<<B, 64, 0, stream>>>(mask, sel_score, kept_pos, kept_cnt);
  outK<<<dim3((KPOST + 255) / 256, B), 256, 0, stream>>>(cls, sel_score, sel_idx, sel_box,
                                                         kept_pos, kept_cnt, out);
}

// Round 5
// 324.961 us; speedup vs baseline: 1.6536x; 1.6536x over previous
//
#include <hip/hip_runtime.h>
#include <stdint.h>

constexpr int B = 4;
constexpr int N = 262144;
constexpr int C = 10;
constexpr int KPRE = 4096;
constexpr int KPOST = 500;
constexpr float ROI_THR = 0.1f;
constexpr float NMS_THR = 0.01f;
constexpr int CAP = 8192;        // compaction capacity (>= KPRE + boundary-bin ties)
constexpr int MASKW = KPRE / 64; // 64 u64 words per mask row

__device__ __forceinline__ uint32_t f2k(float f) {
  uint32_t u = __float_as_uint(f);
  return (u & 0x80000000u) ? ~u : (u | 0x80000000u);
}
__device__ __forceinline__ float k2f(uint32_t k) {
  uint32_t u = (k & 0x80000000u) ? (k ^ 0x80000000u) : ~k;
  return __uint_as_float(u);
}
__device__ __forceinline__ float sigm(float x) { return 1.0f / (1.0f + expf(-x)); }

__device__ __forceinline__ void async_lds16(const void* g, void* l) {
  __builtin_amdgcn_global_load_lds((const __attribute__((address_space(1))) void*)g,
                                   (__attribute__((address_space(3))) void*)l, 16, 0, 0);
}

// Suffix-select on a 256-bin histogram: returns (bin, residual rank). Requires
// blockDim==256; s is 256-u32 LDS scratch, o2 is 2-u32 LDS scratch.
__device__ __forceinline__ uint2 select256(const uint32_t* __restrict__ h, uint32_t R,
                                           uint32_t* s, uint32_t* o2) {
  int t = threadIdx.x;
  s[t] = h[t];
  __syncthreads();
  for (int off = 1; off < 256; off <<= 1) {
    uint32_t v = s[t] + ((t + off < 256) ? s[t + off] : 0u);
    __syncthreads();
    s[t] = v;
    __syncthreads();
  }
  uint32_t suf = s[t];
  uint32_t sufn = (t < 255) ? s[t + 1] : 0u;
  if (suf >= R && R > sufn) {
    o2[0] = (uint32_t)t;
    o2[1] = R - sufn;
  }
  __syncthreads();
  uint2 r;
  r.x = o2[0];
  r.y = o2[1];
  __syncthreads(); // protect scratch reuse
  return r;
}

// ---------------- K0: scores -> sortable keys + LDS-aggregated pass-0 histogram ----------------
__global__ void scoreK(const float* __restrict__ cls, uint32_t* __restrict__ keys,
                       uint32_t* __restrict__ hist0) {
  __shared__ uint32_t h[256];
  int b = blockIdx.y;
  h[threadIdx.x] = 0;
  __syncthreads();
  int base = blockIdx.x * 1024;
#pragma unroll
  for (int kk = 0; kk < 4; ++kk) {
    int n = base + kk * 256 + threadIdx.x;
    const float2* pp = (const float2*)(cls + ((size_t)b * N + n) * C);
    float2 v0 = pp[0], v1 = pp[1], v2 = pp[2], v3 = pp[3], v4 = pp[4];
    float m = sigm(v0.x);
    m = fmaxf(m, sigm(v0.y));
    m = fmaxf(m, sigm(v1.x));
    m = fmaxf(m, sigm(v1.y));
    m = fmaxf(m, sigm(v2.x));
    m = fmaxf(m, sigm(v2.y));
    m = fmaxf(m, sigm(v3.x));
    m = fmaxf(m, sigm(v3.y));
    m = fmaxf(m, sigm(v4.x));
    m = fmaxf(m, sigm(v4.y));
    float s = (m > ROI_THR) ? m : -1.0f;
    uint32_t k = f2k(s);
    keys[(size_t)b * N + n] = k;
    atomicAdd(&h[k >> 24], 1u);
  }
  __syncthreads();
  if (h[threadIdx.x]) atomicAdd(&hist0[b * 256 + threadIdx.x], h[threadIdx.x]);
}

// ---------------- K1: byte-1 histogram among items matching pass-0 prefix ----------------
__global__ void histP1K(const uint32_t* __restrict__ keys, const uint32_t* __restrict__ hist0,
                        uint32_t* __restrict__ hist1) {
  __shared__ uint32_t s[256];
  __shared__ uint32_t o2[2];
  __shared__ uint32_t h[256];
  int b = blockIdx.y;
  uint2 s0 = select256(hist0 + b * 256, (uint32_t)KPRE, s, o2);
  h[threadIdx.x] = 0;
  __syncthreads();
  uint32_t pref = s0.x;
  const uint32_t* kb = keys + (size_t)b * N;
  for (int n = blockIdx.x * 256 + threadIdx.x; n < N; n += gridDim.x * 256) {
    uint32_t k = kb[n];
    if ((k >> 24) == pref) atomicAdd(&h[(k >> 16) & 255u], 1u);
  }
  __syncthreads();
  if (h[threadIdx.x]) atomicAdd(&hist1[b * 256 + threadIdx.x], h[threadIdx.x]);
}

// ---------------- K2: byte-2 histogram among items matching 16-bit prefix ----------------
__global__ void histP2K(const uint32_t* __restrict__ keys, const uint32_t* __restrict__ hist0,
                        const uint32_t* __restrict__ hist1, uint32_t* __restrict__ hist2) {
  __shared__ uint32_t s[256];
  __shared__ uint32_t o2[2];
  __shared__ uint32_t h[256];
  int b = blockIdx.y;
  uint2 s0 = select256(hist0 + b * 256, (uint32_t)KPRE, s, o2);
  uint2 s1 = select256(hist1 + b * 256, s0.y, s, o2);
  h[threadIdx.x] = 0;
  __syncthreads();
  uint32_t pref16 = (s0.x << 8) | s1.x;
  const uint32_t* kb = keys + (size_t)b * N;
  for (int n = blockIdx.x * 256 + threadIdx.x; n < N; n += gridDim.x * 256) {
    uint32_t k = kb[n];
    if ((k >> 16) == pref16) atomicAdd(&h[(k >> 8) & 255u], 1u);
  }
  __syncthreads();
  if (h[threadIdx.x]) atomicAdd(&hist2[b * 256 + threadIdx.x], h[threadIdx.x]);
}

// ---------------- K3: compute 24-bit threshold, compact all keys >= T ----------------
__global__ void compactK(const uint32_t* __restrict__ keys, const uint32_t* __restrict__ hist0,
                         const uint32_t* __restrict__ hist1, const uint32_t* __restrict__ hist2,
                         unsigned long long* __restrict__ list, uint32_t* __restrict__ cnt) {
  __shared__ uint32_t s[256];
  __shared__ uint32_t o2[2];
  int b = blockIdx.y;
  uint2 s0 = select256(hist0 + b * 256, (uint32_t)KPRE, s, o2);
  uint2 s1 = select256(hist1 + b * 256, s0.y, s, o2);
  uint2 s2 = select256(hist2 + b * 256, s1.y, s, o2);
  uint32_t T = (s0.x << 24) | (s1.x << 16) | (s2.x << 8);
  const uint32_t* kb = keys + (size_t)b * N;
  for (int n = blockIdx.x * 256 + threadIdx.x; n < N; n += gridDim.x * 256) {
    uint32_t k = kb[n];
    if (k >= T) {
      uint32_t pos = atomicAdd(&cnt[b], 1u);
      if (pos < CAP)
        list[(size_t)b * CAP + pos] = ((unsigned long long)k << 32) | (uint32_t)(~(uint32_t)n);
    }
  }
}

// ---------------- K4: exact rank by counting (desc by pack = key desc, idx asc) ----------------
// One block per 256-item i-tile; loops all j-tiles with LDS staging; inner reads are
// wave-uniform broadcasts. Plain store (no atomics).
__global__ void rankK(const unsigned long long* __restrict__ list, const uint32_t* __restrict__ cnt,
                      uint32_t* __restrict__ rank) {
  __shared__ unsigned long long lp[256];
  int b = blockIdx.y;
  int cc = (int)min(cnt[b], (uint32_t)CAP);
  if (blockIdx.x * 256 >= cc) return; // block-uniform
  int i = blockIdx.x * 256 + threadIdx.x;
  unsigned long long pi = (i < cc) ? list[(size_t)b * CAP + i] : ~0ull;
  uint32_t c = 0;
  int ntile = (cc + 255) >> 8;
  for (int tb = 0; tb < ntile; ++tb) {
    int j = tb * 256 + threadIdx.x;
    __syncthreads();
    lp[threadIdx.x] = (j < cc) ? list[(size_t)b * CAP + j] : 0ull;
    __syncthreads();
#pragma unroll 8
    for (int jj = 0; jj < 256; ++jj) c += (lp[jj] > pi) ? 1u : 0u;
  }
  if (i < cc) rank[(size_t)b * CAP + i] = c;
}

// ---------------- K5: scatter item -> position rank; gather boxes ----------------
__global__ void scatterK(const unsigned long long* __restrict__ list,
                         const uint32_t* __restrict__ cnt, const uint32_t* __restrict__ rank,
                         const float* __restrict__ boxes, float* __restrict__ sel_score,
                         uint32_t* __restrict__ sel_idx, float* __restrict__ sel_box) {
  int b = blockIdx.y;
  int p = blockIdx.x * 256 + threadIdx.x;
  uint32_t cc = min(cnt[b], (uint32_t)CAP);
  if (p >= (int)cc) return;
  unsigned long long pk = list[(size_t)b * CAP + p];
  uint32_t r = rank[(size_t)b * CAP + p];
  if (r >= (uint32_t)KPRE) return;
  uint32_t key = (uint32_t)(pk >> 32);
  uint32_t idx = ~(uint32_t)pk;
  sel_score[b * KPRE + r] = k2f(key);
  sel_idx[b * KPRE + r] = idx;
  const float* src = boxes + ((size_t)b * N + idx) * 7;
  float* dst = sel_box + ((size_t)b * KPRE + r) * 8;
#pragma unroll
  for (int c = 0; c < 7; ++c) dst[c] = src[c];
  dst[7] = 0.f;
}

// ---------------- K6: pairwise IoU suppression bitmask (2D tiled) ----------------
__global__ void maskK(const float* __restrict__ sel_box, unsigned long long* __restrict__ mask) {
  int b = blockIdx.z;
  int bi = blockIdx.x;
  int w = blockIdx.y;
  int t = threadIdx.x;
  int i = bi * 256 + t;
  int j0 = w * 64;
  unsigned long long* dst = mask + ((size_t)b * KPRE + i) * MASKW + w;
  if (j0 + 63 <= bi * 256) { // whole tile is j <= i: no suppression bits
    *dst = 0ull;
    return;
  }
  __shared__ float jx1[64], jx2[64], jy1[64], jy2[64], ja[64];
  if (t < 64) {
    const float4* bj = (const float4*)(sel_box + ((size_t)b * KPRE + j0 + t) * 8);
    float4 lo = bj[0], hi = bj[1];
    float xj = lo.x, yj = lo.y, dxj = lo.w, dyj = hi.x;
    float hxj = __fmul_rn(dxj, 0.5f), hyj = __fmul_rn(dyj, 0.5f);
    jx1[t] = __fsub_rn(xj, hxj);
    jx2[t] = __fadd_rn(xj, hxj);
    jy1[t] = __fsub_rn(yj, hyj);
    jy2[t] = __fadd_rn(yj, hyj);
    ja[t] = __fmul_rn(dxj, dyj);
  }
  __syncthreads();
  const float4* myb = (const float4*)(sel_box + ((size_t)b * KPRE + i) * 8);
  float4 lo = myb[0], hi = myb[1];
  float x = lo.x, y = lo.y, dx = lo.w, dy = hi.x;
  float hx = __fmul_rn(dx, 0.5f), hy = __fmul_rn(dy, 0.5f);
  float x1i = __fsub_rn(x, hx), x2i = __fadd_rn(x, hx);
  float y1i = __fsub_rn(y, hy), y2i = __fadd_rn(y, hy);
  float ai = __fmul_rn(dx, dy);
  unsigned long long wacc = 0ull;
#pragma unroll 16
  for (int jj = 0; jj < 64; ++jj) {
    int j = j0 + jj;
    float xx1 = fmaxf(x1i, jx1[jj]);
    float xx2 = fminf(x2i, jx2[jj]);
    float yy1 = fmaxf(y1i, jy1[jj]);
    float yy2 = fminf(y2i, jy2[jj]);
    float ix = fmaxf(__fsub_rn(xx2, xx1), 0.0f);
    float iy = fmaxf(__fsub_rn(yy2, yy1), 0.0f);
    float inter = __fmul_rn(ix, iy);
    float uni = __fsub_rn(__fadd_rn(ai, ja[jj]), inter);
    float iou = inter / fmaxf(uni, 1e-6f);
    bool sup = (iou > NMS_THR) && (j > i);
    wacc |= ((unsigned long long)(sup ? 1u : 0u)) << jj;
  }
  *dst = wacc;
}

// ---------------- K7: greedy NMS scan, group-parallel (1 wave / batch) ----------------
__global__ void nmsK(const unsigned long long* __restrict__ mask,
                     const float* __restrict__ sel_score,
                     uint32_t* __restrict__ kept_pos, uint32_t* __restrict__ kept_cnt) {
  __shared__ unsigned long long lds[2][64][64]; // 64 KiB double buffer
  int b = blockIdx.x;
  int t = threadIdx.x; // lane 0..63; owns remv word t

  unsigned long long cand = 0ull;
  for (int k = 0; k < 64; ++k) {
    float s = sel_score[b * KPRE + k * 64 + t];
    unsigned long long bal = __ballot(s > ROI_THR);
    if (t == k) cand = bal;
  }

  const unsigned long long* mb = mask + (size_t)b * KPRE * MASKW;
  unsigned long long remv = 0ull;
  int kc = 0;

  auto prefetch = [&](int g, int buf2) {
    const char* base = (const char*)(mb + (size_t)g * 64 * MASKW);
#pragma unroll
    for (int p = 0; p < 32; ++p)
      async_lds16(base + (size_t)p * 1024 + (size_t)t * 16, &lds[buf2][p * 2][0]);
  };

  prefetch(0, 0);
  for (int g = 0; g < 64; ++g) {
    int buf = g & 1;
    asm volatile("s_waitcnt vmcnt(0)" ::: "memory"); // current buf ready
    if (g + 1 < 64) prefetch(g + 1, buf ^ 1);        // overlap next with processing

    unsigned long long cw = cand & ~remv;
    unsigned long long aw = (unsigned long long)__shfl((long long)cw, g, 64);
    if (aw) {
      unsigned long long m = lds[buf][t][g]; // who I kill within group (bits > t)
      unsigned long long K = __ballot((m & aw) != 0ull);
      unsigned long long alive = aw;
      unsigned long long rem = aw & K;
      if (rem) {
        bool deadf = ((aw >> t) & 1ull) == 0ull;
        while (rem) {
          int s = __ffsll((long long)rem) - 1;
          rem &= rem - 1ull;
          if ((alive >> s) & 1ull) { // s is final-alive here (ascending order)
            unsigned long long row_s = lds[buf][s][g]; // broadcast read
            deadf = deadf || (((row_s >> t) & 1ull) != 0ull);
            alive = __ballot(!deadf);
            rem &= alive;
          }
        }
      }
      int grp = __popcll(alive);
      if ((alive >> t) & 1ull) {
        int rk = __popcll(alive & ((1ull << t) - 1ull));
        if (kc + rk < KPOST) kept_pos[b * KPOST + kc + rk] = g * 64 + t;
      }
      unsigned long long acc = 0ull, a2 = alive;
      while (a2) {
        int s2 = __ffsll((long long)a2) - 1;
        a2 &= a2 - 1ull;
        acc |= lds[buf][s2][t];
      }
      remv |= acc;
      kc += grp;
      if (kc >= KPOST) break;
    }
  }
  asm volatile("s_waitcnt vmcnt(0)" ::: "memory"); // drain in-flight prefetch
  if (t == 0) kept_cnt[b] = (uint32_t)min(kc, KPOST);
}

// ---------------- K8: emit outputs ----------------
__global__ void outK(const float* __restrict__ cls,
                     const float* __restrict__ sel_score, const uint32_t* __restrict__ sel_idx,
                     const float* __restrict__ sel_box,
                     const uint32_t* __restrict__ kept_pos, const uint32_t* __restrict__ kept_cnt,
                     float* __restrict__ out) {
  int b = blockIdx.y;
  int s = blockIdx.x * blockDim.x + threadIdx.x;
  if (s >= KPOST) return;
  float* oS = out;                             // (B, KPOST)
  float* oB = out + B * KPOST;                 // (B, KPOST, 7)
  float* oL = out + B * KPOST + B * KPOST * 7; // (B, KPOST)
  uint32_t kcnt = kept_cnt[b];
  if (s < (int)kcnt) {
    uint32_t pos = kept_pos[b * KPOST + s];
    oS[b * KPOST + s] = sel_score[b * KPRE + pos];
    const float* box = sel_box + ((size_t)b * KPRE + pos) * 8;
    float* dst = oB + ((size_t)b * KPOST + s) * 7;
#pragma unroll
    for (int c = 0; c < 7; ++c) dst[c] = box[c];
    uint32_t idx = sel_idx[b * KPRE + pos];
    const float* p = cls + ((size_t)b * N + idx) * C;
    float bestv = sigm(p[0]);
    int bestc = 0;
#pragma unroll
    for (int c = 1; c < C; ++c) {
      float v = sigm(p[c]);
      if (v > bestv) { bestv = v; bestc = c; }
    }
    oL[b * KPOST + s] = (float)bestc;
  } else {
    oS[b * KPOST + s] = 0.0f;
    float* dst = oB + ((size_t)b * KPOST + s) * 7;
#pragma unroll
    for (int c = 0; c < 7; ++c) dst[c] = 0.0f;
    oL[b * KPOST + s] = -1.0f;
  }
}

__global__ void sentinelK(float* out, int n) {
  int i = blockIdx.x * blockDim.x + threadIdx.x;
  if (i < n) out[i] = 1337.0f;
}

extern "C" void kernel_launch(void* const* d_in, const int* in_sizes, int n_in,
                              void* d_out, int out_size, void* d_ws, size_t ws_size,
                              hipStream_t stream) {
  const float* cls = (const float*)d_in[0];
  const float* boxes = (const float*)d_in[1];
  float* out = (float*)d_out;

  char* ws = (char*)d_ws;
  size_t off = 0;
  auto alloc = [&](size_t bytes) -> void* {
    void* p = ws + off;
    off = (off + bytes + 255) & ~(size_t)255;
    return p;
  };
  unsigned long long* mask = (unsigned long long*)alloc((size_t)B * KPRE * MASKW * 8); // 8 MB
  unsigned long long* list = (unsigned long long*)alloc((size_t)B * CAP * 8);
  uint32_t* keys = (uint32_t*)alloc((size_t)B * N * 4);
  float* sel_box = (float*)alloc((size_t)B * KPRE * 8 * 4);
  float* sel_score = (float*)alloc((size_t)B * KPRE * 4);
  uint32_t* sel_idx = (uint32_t*)alloc((size_t)B * KPRE * 4);
  uint32_t* kept_pos = (uint32_t*)alloc((size_t)B * KPOST * 4);
  uint32_t* kept_cnt = (uint32_t*)alloc(B * 4); // NOT aliased: written by nmsK after maskK

  // Aliases into the mask region — all dead before maskK writes mask:
  //   hist0/1/2 (B*256 u32 each), cnt (B u32): zeroed by memset, read before maskK.
  //   rank (B*CAP u32): plain-stored by rankK, read by scatterK before maskK.
  uint32_t* hist0 = (uint32_t*)mask;
  uint32_t* hist1 = hist0 + B * 256;
  uint32_t* hist2 = hist1 + B * 256;
  uint32_t* cnt = hist2 + B * 256;
  uint32_t* rank = (uint32_t*)((char*)mask + 16384);
  size_t zbytes = (size_t)(3 * B * 256 + B) * 4; // hists + cnt

  if (off > ws_size) {
    sentinelK<<<dim3((out_size + 255) / 256), 256, 0, stream>>>(out, out_size);
    return;
  }

  hipMemsetAsync(mask, 0, zbytes, stream);
  scoreK<<<dim3(N / 1024, B), 256, 0, stream>>>(cls, keys, hist0);
  histP1K<<<dim3(64, B), 256, 0, stream>>>(keys, hist0, hist1);
  histP2K<<<dim3(64, B), 256, 0, stream>>>(keys, hist0, hist1, hist2);
  compactK<<<dim3(64, B), 256, 0, stream>>>(keys, hist0, hist1, hist2, list, cnt);
  rankK<<<dim3(CAP / 256, B), 256, 0, stream>>>(list, cnt, rank);
  scatterK<<<dim3(CAP / 256, B), 256, 0, stream>>>(list, cnt, rank, boxes, sel_score, sel_idx,
                                                   sel_box);
  maskK<<<dim3(16, 64, B), 256, 0, stream>>>(sel_box, mask);
  nmsK<<<B, 64, 0, stream>>>(mask, sel_score, kept_pos, kept_cnt);
  outK<<<dim3((KPOST + 255) / 256, B), 256, 0, stream>>>(cls, sel_score, sel_idx, sel_box,
                                                         kept_pos, kept_cnt, out);
}

// Round 6
// 216.103 us; speedup vs baseline: 2.4865x; 1.5037x over previous
//
#include <hip/hip_runtime.h>
#include <stdint.h>

constexpr int B = 4;
constexpr int N = 262144;
constexpr int C = 10;
constexpr int KPRE = 4096;
constexpr int KPOST = 500;
constexpr float ROI_THR = 0.1f;
constexpr float NMS_THR = 0.01f;
constexpr int CAP = 8192;        // compaction capacity (>= KPRE + boundary-bin ties)
constexpr int MASKW = KPRE / 64; // 64 u64 words per mask row

__device__ __forceinline__ uint32_t f2k(float f) {
  uint32_t u = __float_as_uint(f);
  return (u & 0x80000000u) ? ~u : (u | 0x80000000u);
}
__device__ __forceinline__ float k2f(uint32_t k) {
  uint32_t u = (k & 0x80000000u) ? (k ^ 0x80000000u) : ~k;
  return __uint_as_float(u);
}
__device__ __forceinline__ float sigm(float x) { return 1.0f / (1.0f + expf(-x)); }

__device__ __forceinline__ void async_lds16(const void* g, void* l) {
  __builtin_amdgcn_global_load_lds((const __attribute__((address_space(1))) void*)g,
                                   (__attribute__((address_space(3))) void*)l, 16, 0, 0);
}

// Suffix-select on a 256-bin histogram: returns (bin, residual rank). blockDim==256.
__device__ __forceinline__ uint2 select256(const uint32_t* __restrict__ h, uint32_t R,
                                           uint32_t* s, uint32_t* o2) {
  int t = threadIdx.x;
  s[t] = h[t];
  __syncthreads();
  for (int off = 1; off < 256; off <<= 1) {
    uint32_t v = s[t] + ((t + off < 256) ? s[t + off] : 0u);
    __syncthreads();
    s[t] = v;
    __syncthreads();
  }
  uint32_t suf = s[t];
  uint32_t sufn = (t < 255) ? s[t + 1] : 0u;
  if (suf >= R && R > sufn) {
    o2[0] = (uint32_t)t;
    o2[1] = R - sufn;
  }
  __syncthreads();
  uint2 r;
  r.x = o2[0];
  r.y = o2[1];
  __syncthreads(); // protect scratch reuse
  return r;
}

// ---------------- K0: LDS-staged coalesced scores -> keys + pass-0 histogram ----------------
__global__ void scoreK(const float* __restrict__ cls, uint32_t* __restrict__ keys,
                       uint32_t* __restrict__ hist0) {
  __shared__ float ls[2560]; // 256 items x 10 classes
  __shared__ uint32_t h[256];
  int b = blockIdx.y;
  int t = threadIdx.x;
  h[t] = 0;
  size_t base = ((size_t)b * N + (size_t)blockIdx.x * 256) * C;
  const float2* g2 = (const float2*)(cls + base);
  float2* l2 = (float2*)ls;
#pragma unroll
  for (int r = 0; r < 5; ++r) l2[r * 256 + t] = g2[r * 256 + t]; // coalesced 512B/wave
  __syncthreads();
  const float* mine = ls + t * 10;
  float m = sigm(mine[0]);
#pragma unroll
  for (int c = 1; c < C; ++c) m = fmaxf(m, sigm(mine[c]));
  float sc = (m > ROI_THR) ? m : -1.0f;
  uint32_t k = f2k(sc);
  keys[(size_t)b * N + blockIdx.x * 256 + t] = k;
  atomicAdd(&h[k >> 24], 1u);
  __syncthreads();
  if (h[t]) atomicAdd(&hist0[b * 256 + t], h[t]);
}

// ---------------- K1: byte-1 histogram among items matching pass-0 byte ----------------
__global__ void histP1K(const uint32_t* __restrict__ keys, const uint32_t* __restrict__ hist0,
                        uint32_t* __restrict__ hist1) {
  __shared__ uint32_t s[256];
  __shared__ uint32_t o2[2];
  __shared__ uint32_t h[256];
  int b = blockIdx.y;
  int t = threadIdx.x;
  uint2 s0 = select256(hist0 + b * 256, (uint32_t)KPRE, s, o2);
  h[t] = 0;
  __syncthreads();
  uint32_t pref = s0.x;
  const uint4* kb4 = (const uint4*)(keys + (size_t)b * N);
#pragma unroll
  for (int r = 0; r < 2; ++r) {
    uint4 kv = kb4[blockIdx.x * 512 + r * 256 + t];
#pragma unroll
    for (int j = 0; j < 4; ++j) {
      uint32_t k = (&kv.x)[j];
      if ((k >> 24) == pref) atomicAdd(&h[(k >> 16) & 255u], 1u);
    }
  }
  __syncthreads();
  if (h[t]) atomicAdd(&hist1[b * 256 + t], h[t]);
}

// ---------------- K2: 16-bit threshold; block-aggregated stream compaction ----------------
__global__ void compactK(const uint32_t* __restrict__ keys, const uint32_t* __restrict__ hist0,
                         const uint32_t* __restrict__ hist1, unsigned long long* __restrict__ list,
                         uint32_t* __restrict__ cnt) {
  __shared__ uint32_t s[256];
  __shared__ uint32_t o2[2];
  __shared__ uint32_t scan[256];
  __shared__ uint32_t baseSh;
  int b = blockIdx.y;
  int t = threadIdx.x;
  uint2 s0 = select256(hist0 + b * 256, (uint32_t)KPRE, s, o2);
  uint2 s1 = select256(hist1 + b * 256, s0.y, s, o2);
  uint32_t T = ((s0.x << 8) | s1.x) << 16;
  const uint4* kb4 = (const uint4*)(keys + (size_t)b * N);
  uint4 kv[4];
#pragma unroll
  for (int r = 0; r < 4; ++r) kv[r] = kb4[blockIdx.x * 1024 + r * 256 + t];
  uint32_t c = 0;
#pragma unroll
  for (int r = 0; r < 4; ++r)
#pragma unroll
    for (int j = 0; j < 4; ++j) c += ((&kv[r].x)[j] >= T) ? 1u : 0u;
  scan[t] = c;
  __syncthreads();
  for (int off = 1; off < 256; off <<= 1) {
    uint32_t v = scan[t] + ((t >= off) ? scan[t - off] : 0u);
    __syncthreads();
    scan[t] = v;
    __syncthreads();
  }
  uint32_t excl = scan[t] - c;
  if (t == 255) baseSh = atomicAdd(&cnt[b], scan[255]);
  __syncthreads();
  uint32_t pos = baseSh + excl;
#pragma unroll
  for (int r = 0; r < 4; ++r)
#pragma unroll
    for (int j = 0; j < 4; ++j) {
      uint32_t k = (&kv[r].x)[j];
      if (k >= T) {
        uint32_t n = (blockIdx.x * 1024 + r * 256 + t) * 4 + j;
        if (pos < CAP)
          list[(size_t)b * CAP + pos] = ((unsigned long long)k << 32) | (uint32_t)(~n);
        pos++;
      }
    }
}

// ---------------- K3: exact rank by counting (desc by pack = key desc, idx asc) ----------------
__global__ void rankK(const unsigned long long* __restrict__ list, const uint32_t* __restrict__ cnt,
                      uint32_t* __restrict__ rank) {
  __shared__ unsigned long long lp[256];
  int b = blockIdx.y;
  int cc = (int)min(cnt[b], (uint32_t)CAP);
  if (blockIdx.x * 256 >= cc) return; // block-uniform
  int i = blockIdx.x * 256 + threadIdx.x;
  unsigned long long pi = (i < cc) ? list[(size_t)b * CAP + i] : ~0ull;
  uint32_t c = 0;
  int ntile = (cc + 255) >> 8;
  for (int tb = 0; tb < ntile; ++tb) {
    int j = tb * 256 + threadIdx.x;
    __syncthreads();
    lp[threadIdx.x] = (j < cc) ? list[(size_t)b * CAP + j] : 0ull;
    __syncthreads();
#pragma unroll 8
    for (int jj = 0; jj < 256; ++jj) c += (lp[jj] > pi) ? 1u : 0u;
  }
  if (i < cc) rank[(size_t)b * CAP + i] = c;
}

// ---------------- K4: scatter item -> position rank; gather boxes ----------------
__global__ void scatterK(const unsigned long long* __restrict__ list,
                         const uint32_t* __restrict__ cnt, const uint32_t* __restrict__ rank,
                         const float* __restrict__ boxes, float* __restrict__ sel_score,
                         uint32_t* __restrict__ sel_idx, float* __restrict__ sel_box) {
  int b = blockIdx.y;
  int p = blockIdx.x * 256 + threadIdx.x;
  uint32_t cc = min(cnt[b], (uint32_t)CAP);
  if (p >= (int)cc) return;
  unsigned long long pk = list[(size_t)b * CAP + p];
  uint32_t r = rank[(size_t)b * CAP + p];
  if (r >= (uint32_t)KPRE) return;
  uint32_t key = (uint32_t)(pk >> 32);
  uint32_t idx = ~(uint32_t)pk;
  sel_score[b * KPRE + r] = k2f(key);
  sel_idx[b * KPRE + r] = idx;
  const float* src = boxes + ((size_t)b * N + idx) * 7;
  float* dst = sel_box + ((size_t)b * KPRE + r) * 8;
#pragma unroll
  for (int c = 0; c < 7; ++c) dst[c] = src[c];
  dst[7] = 0.f;
}

// ---------------- K5: pairwise IoU suppression bitmask (2D tiled) ----------------
__global__ void maskK(const float* __restrict__ sel_box, unsigned long long* __restrict__ mask) {
  int b = blockIdx.z;
  int bi = blockIdx.x;
  int w = blockIdx.y;
  int t = threadIdx.x;
  int i = bi * 256 + t;
  int j0 = w * 64;
  unsigned long long* dst = mask + ((size_t)b * KPRE + i) * MASKW + w;
  if (j0 + 63 <= bi * 256) { // whole tile is j <= i: no suppression bits
    *dst = 0ull;
    return;
  }
  __shared__ float jx1[64], jx2[64], jy1[64], jy2[64], ja[64];
  if (t < 64) {
    const float4* bj = (const float4*)(sel_box + ((size_t)b * KPRE + j0 + t) * 8);
    float4 lo = bj[0], hi = bj[1];
    float xj = lo.x, yj = lo.y, dxj = lo.w, dyj = hi.x;
    float hxj = __fmul_rn(dxj, 0.5f), hyj = __fmul_rn(dyj, 0.5f);
    jx1[t] = __fsub_rn(xj, hxj);
    jx2[t] = __fadd_rn(xj, hxj);
    jy1[t] = __fsub_rn(yj, hyj);
    jy2[t] = __fadd_rn(yj, hyj);
    ja[t] = __fmul_rn(dxj, dyj);
  }
  __syncthreads();
  const float4* myb = (const float4*)(sel_box + ((size_t)b * KPRE + i) * 8);
  float4 lo = myb[0], hi = myb[1];
  float x = lo.x, y = lo.y, dx = lo.w, dy = hi.x;
  float hx = __fmul_rn(dx, 0.5f), hy = __fmul_rn(dy, 0.5f);
  float x1i = __fsub_rn(x, hx), x2i = __fadd_rn(x, hx);
  float y1i = __fsub_rn(y, hy), y2i = __fadd_rn(y, hy);
  float ai = __fmul_rn(dx, dy);
  unsigned long long wacc = 0ull;
#pragma unroll 16
  for (int jj = 0; jj < 64; ++jj) {
    int j = j0 + jj;
    float xx1 = fmaxf(x1i, jx1[jj]);
    float xx2 = fminf(x2i, jx2[jj]);
    float yy1 = fmaxf(y1i, jy1[jj]);
    float yy2 = fminf(y2i, jy2[jj]);
    float ix = fmaxf(__fsub_rn(xx2, xx1), 0.0f);
    float iy = fmaxf(__fsub_rn(yy2, yy1), 0.0f);
    float inter = __fmul_rn(ix, iy);
    float uni = __fsub_rn(__fadd_rn(ai, ja[jj]), inter);
    float iou = inter / fmaxf(uni, 1e-6f);
    bool sup = (iou > NMS_THR) && (j > i);
    wacc |= ((unsigned long long)(sup ? 1u : 0u)) << jj;
  }
  *dst = wacc;
}

// ---------------- K6: greedy NMS scan, group-parallel (1 wave / batch) ----------------
__global__ void nmsK(const unsigned long long* __restrict__ mask,
                     const float* __restrict__ sel_score,
                     uint32_t* __restrict__ kept_pos, uint32_t* __restrict__ kept_cnt) {
  __shared__ unsigned long long lds[2][64][64]; // 64 KiB double buffer
  int b = blockIdx.x;
  int t = threadIdx.x; // lane 0..63; owns remv word t

  unsigned long long cand = 0ull;
  for (int k = 0; k < 64; ++k) {
    float s = sel_score[b * KPRE + k * 64 + t];
    unsigned long long bal = __ballot(s > ROI_THR);
    if (t == k) cand = bal;
  }

  const unsigned long long* mb = mask + (size_t)b * KPRE * MASKW;
  unsigned long long remv = 0ull;
  int kc = 0;

  auto prefetch = [&](int g, int buf2) {
    const char* base = (const char*)(mb + (size_t)g * 64 * MASKW);
#pragma unroll
    for (int p = 0; p < 32; ++p)
      async_lds16(base + (size_t)p * 1024 + (size_t)t * 16, &lds[buf2][p * 2][0]);
  };

  prefetch(0, 0);
  for (int g = 0; g < 64; ++g) {
    int buf = g & 1;
    asm volatile("s_waitcnt vmcnt(0)" ::: "memory"); // current buf ready
    if (g + 1 < 64) prefetch(g + 1, buf ^ 1);        // overlap next with processing

    unsigned long long cw = cand & ~remv;
    unsigned long long aw = (unsigned long long)__shfl((long long)cw, g, 64);
    if (aw) {
      unsigned long long m = lds[buf][t][g]; // who I kill within group (bits > t)
      unsigned long long K = __ballot((m & aw) != 0ull);
      unsigned long long alive = aw;
      unsigned long long rem = aw & K;
      if (rem) {
        bool deadf = ((aw >> t) & 1ull) == 0ull;
        while (rem) {
          int s = __ffsll((long long)rem) - 1;
          rem &= rem - 1ull;
          if ((alive >> s) & 1ull) { // s is final-alive here (ascending order)
            unsigned long long row_s = lds[buf][s][g]; // broadcast read
            deadf = deadf || (((row_s >> t) & 1ull) != 0ull);
            alive = __ballot(!deadf);
            rem &= alive;
          }
        }
      }
      int grp = __popcll(alive);
      if ((alive >> t) & 1ull) {
        int rk = __popcll(alive & ((1ull << t) - 1ull));
        if (kc + rk < KPOST) kept_pos[b * KPOST + kc + rk] = g * 64 + t;
      }
      unsigned long long acc = 0ull, a2 = alive;
      while (a2) {
        int s2 = __ffsll((long long)a2) - 1;
        a2 &= a2 - 1ull;
        acc |= lds[buf][s2][t];
      }
      remv |= acc;
      kc += grp;
      if (kc >= KPOST) break;
    }
  }
  asm volatile("s_waitcnt vmcnt(0)" ::: "memory"); // drain in-flight prefetch
  if (t == 0) kept_cnt[b] = (uint32_t)min(kc, KPOST);
}

// ---------------- K7: emit outputs ----------------
__global__ void outK(const float* __restrict__ cls,
                     const float* __restrict__ sel_score, const uint32_t* __restrict__ sel_idx,
                     const float* __restrict__ sel_box,
                     const uint32_t* __restrict__ kept_pos, const uint32_t* __restrict__ kept_cnt,
                     float* __restrict__ out) {
  int b = blockIdx.y;
  int s = blockIdx.x * blockDim.x + threadIdx.x;
  if (s >= KPOST) return;
  float* oS = out;                             // (B, KPOST)
  float* oB = out + B * KPOST;                 // (B, KPOST, 7)
  float* oL = out + B * KPOST + B * KPOST * 7; // (B, KPOST)
  uint32_t kcnt = kept_cnt[b];
  if (s < (int)kcnt) {
    uint32_t pos = kept_pos[b * KPOST + s];
    oS[b * KPOST + s] = sel_score[b * KPRE + pos];
    const float* box = sel_box + ((size_t)b * KPRE + pos) * 8;
    float* dst = oB + ((size_t)b * KPOST + s) * 7;
#pragma unroll
    for (int c = 0; c < 7; ++c) dst[c] = box[c];
    uint32_t idx = sel_idx[b * KPRE + pos];
    const float* p = cls + ((size_t)b * N + idx) * C;
    float bestv = sigm(p[0]);
    int bestc = 0;
#pragma unroll
    for (int c = 1; c < C; ++c) {
      float v = sigm(p[c]);
      if (v > bestv) { bestv = v; bestc = c; }
    }
    oL[b * KPOST + s] = (float)bestc;
  } else {
    oS[b * KPOST + s] = 0.0f;
    float* dst = oB + ((size_t)b * KPOST + s) * 7;
#pragma unroll
    for (int c = 0; c < 7; ++c) dst[c] = 0.0f;
    oL[b * KPOST + s] = -1.0f;
  }
}

__global__ void sentinelK(float* out, int n) {
  int i = blockIdx.x * blockDim.x + threadIdx.x;
  if (i < n) out[i] = 1337.0f;
}

extern "C" void kernel_launch(void* const* d_in, const int* in_sizes, int n_in,
                              void* d_out, int out_size, void* d_ws, size_t ws_size,
                              hipStream_t stream) {
  const float* cls = (const float*)d_in[0];
  const float* boxes = (const float*)d_in[1];
  float* out = (float*)d_out;

  char* ws = (char*)d_ws;
  size_t off = 0;
  auto alloc = [&](size_t bytes) -> void* {
    void* p = ws + off;
    off = (off + bytes + 255) & ~(size_t)255;
    return p;
  };
  unsigned long long* mask = (unsigned long long*)alloc((size_t)B * KPRE * MASKW * 8); // 8 MB
  unsigned long long* list = (unsigned long long*)alloc((size_t)B * CAP * 8);
  uint32_t* keys = (uint32_t*)alloc((size_t)B * N * 4);
  float* sel_box = (float*)alloc((size_t)B * KPRE * 8 * 4);
  float* sel_score = (float*)alloc((size_t)B * KPRE * 4);
  uint32_t* sel_idx = (uint32_t*)alloc((size_t)B * KPRE * 4);
  uint32_t* kept_pos = (uint32_t*)alloc((size_t)B * KPOST * 4);
  uint32_t* kept_cnt = (uint32_t*)alloc(B * 4); // NOT aliased: written by nmsK after maskK

  // Aliases into the mask region — all dead before maskK writes mask:
  //   hist0/1 (B*256 u32 each), cnt (B u32): zeroed by memset, read before maskK.
  //   rank (B*CAP u32): plain-stored by rankK, read by scatterK before maskK.
  uint32_t* hist0 = (uint32_t*)mask;
  uint32_t* hist1 = hist0 + B * 256;
  uint32_t* cnt = hist1 + B * 256;
  uint32_t* rank = (uint32_t*)((char*)mask + 16384);
  size_t zbytes = 12288; // covers hist0+hist1+cnt

  if (off > ws_size) {
    sentinelK<<<dim3((out_size + 255) / 256), 256, 0, stream>>>(out, out_size);
    return;
  }

  hipMemsetAsync(mask, 0, zbytes, stream);
  scoreK<<<dim3(N / 256, B), 256, 0, stream>>>(cls, keys, hist0);
  histP1K<<<dim3(N / 2048, B), 256, 0, stream>>>(keys, hist0, hist1);
  compactK<<<dim3(N / 4096, B), 256, 0, stream>>>(keys, hist0, hist1, list, cnt);
  rankK<<<dim3(CAP / 256, B), 256, 0, stream>>>(list, cnt, rank);
  scatterK<<<dim3(CAP / 256, B), 256, 0, stream>>>(list, cnt, rank, boxes, sel_score, sel_idx,
                                                   sel_box);
  maskK<<<dim3(16, 64, B), 256, 0, stream>>>(sel_box, mask);
  nmsK<<<B, 64, 0, stream>>>(mask, sel_score, kept_pos, kept_cnt);
  outK<<<dim3((KPOST + 255) / 256, B), 256, 0, stream>>>(cls, sel_score, sel_idx, sel_box,
                                                         kept_pos, kept_cnt, out);
}

// Round 7
// 166.278 us; speedup vs baseline: 3.2316x; 1.2996x over previous
//
#include <hip/hip_runtime.h>
#include <stdint.h>

constexpr int B = 4;
constexpr int N = 262144;
constexpr int C = 10;
constexpr int KPRE = 4096;
constexpr int KPOST = 500;
constexpr float ROI_THR = 0.1f;
constexpr float NMS_THR = 0.01f;
constexpr int CAP = 8192;        // compaction capacity (>= KPRE + boundary-bin ties)
constexpr int MASKW = KPRE / 64; // 64 u64 words per mask row
constexpr int RJT = 2;           // j-tiles per rankK block

__device__ __forceinline__ uint32_t f2k(float f) {
  uint32_t u = __float_as_uint(f);
  return (u & 0x80000000u) ? ~u : (u | 0x80000000u);
}
__device__ __forceinline__ float k2f(uint32_t k) {
  uint32_t u = (k & 0x80000000u) ? (k ^ 0x80000000u) : ~k;
  return __uint_as_float(u);
}
__device__ __forceinline__ float sigm(float x) { return 1.0f / (1.0f + expf(-x)); }

__device__ __forceinline__ void async_lds16(const void* g, void* l) {
  __builtin_amdgcn_global_load_lds((const __attribute__((address_space(1))) void*)g,
                                   (__attribute__((address_space(3))) void*)l, 16, 0, 0);
}

// Suffix-select on a 256-bin histogram: returns (bin, residual rank). blockDim==256.
__device__ __forceinline__ uint2 select256(const uint32_t* __restrict__ h, uint32_t R,
                                           uint32_t* s, uint32_t* o2) {
  int t = threadIdx.x;
  s[t] = h[t];
  __syncthreads();
  for (int off = 1; off < 256; off <<= 1) {
    uint32_t v = s[t] + ((t + off < 256) ? s[t + off] : 0u);
    __syncthreads();
    s[t] = v;
    __syncthreads();
  }
  uint32_t suf = s[t];
  uint32_t sufn = (t < 255) ? s[t + 1] : 0u;
  if (suf >= R && R > sufn) {
    o2[0] = (uint32_t)t;
    o2[1] = R - sufn;
  }
  __syncthreads();
  uint2 r;
  r.x = o2[0];
  r.y = o2[1];
  __syncthreads(); // protect scratch reuse
  return r;
}

// ---------------- K0: LDS-staged coalesced scores -> keys + pass-0 histogram ----------------
__global__ void scoreK(const float* __restrict__ cls, uint32_t* __restrict__ keys,
                       uint32_t* __restrict__ hist0) {
  __shared__ float ls[2560]; // 256 items x 10 classes
  __shared__ uint32_t h[256];
  int b = blockIdx.y;
  int t = threadIdx.x;
  h[t] = 0;
  size_t base = ((size_t)b * N + (size_t)blockIdx.x * 256) * C;
  const float2* g2 = (const float2*)(cls + base);
  float2* l2 = (float2*)ls;
#pragma unroll
  for (int r = 0; r < 5; ++r) l2[r * 256 + t] = g2[r * 256 + t]; // coalesced 512B/wave
  __syncthreads();
  const float* mine = ls + t * 10;
  float m = sigm(mine[0]);
#pragma unroll
  for (int c = 1; c < C; ++c) m = fmaxf(m, sigm(mine[c]));
  float sc = (m > ROI_THR) ? m : -1.0f;
  uint32_t k = f2k(sc);
  keys[(size_t)b * N + blockIdx.x * 256 + t] = k;
  atomicAdd(&h[k >> 24], 1u);
  __syncthreads();
  if (h[t]) atomicAdd(&hist0[b * 256 + t], h[t]);
}

// ---------------- K1: byte-1 histogram among items matching pass-0 byte ----------------
__global__ void histP1K(const uint32_t* __restrict__ keys, const uint32_t* __restrict__ hist0,
                        uint32_t* __restrict__ hist1) {
  __shared__ uint32_t s[256];
  __shared__ uint32_t o2[2];
  __shared__ uint32_t h[256];
  int b = blockIdx.y;
  int t = threadIdx.x;
  uint2 s0 = select256(hist0 + b * 256, (uint32_t)KPRE, s, o2);
  h[t] = 0;
  __syncthreads();
  uint32_t pref = s0.x;
  const uint4* kb4 = (const uint4*)(keys + (size_t)b * N);
#pragma unroll
  for (int r = 0; r < 2; ++r) {
    uint4 kv = kb4[blockIdx.x * 512 + r * 256 + t];
#pragma unroll
    for (int j = 0; j < 4; ++j) {
      uint32_t k = (&kv.x)[j];
      if ((k >> 24) == pref) atomicAdd(&h[(k >> 16) & 255u], 1u);
    }
  }
  __syncthreads();
  if (h[t]) atomicAdd(&hist1[b * 256 + t], h[t]);
}

// ---------------- K2: 16-bit threshold; block-aggregated stream compaction ----------------
__global__ void compactK(const uint32_t* __restrict__ keys, const uint32_t* __restrict__ hist0,
                         const uint32_t* __restrict__ hist1, unsigned long long* __restrict__ list,
                         uint32_t* __restrict__ cnt) {
  __shared__ uint32_t s[256];
  __shared__ uint32_t o2[2];
  __shared__ uint32_t scan[256];
  __shared__ uint32_t baseSh;
  int b = blockIdx.y;
  int t = threadIdx.x;
  uint2 s0 = select256(hist0 + b * 256, (uint32_t)KPRE, s, o2);
  uint2 s1 = select256(hist1 + b * 256, s0.y, s, o2);
  uint32_t T = ((s0.x << 8) | s1.x) << 16;
  const uint4* kb4 = (const uint4*)(keys + (size_t)b * N);
  uint4 kv[4];
#pragma unroll
  for (int r = 0; r < 4; ++r) kv[r] = kb4[blockIdx.x * 1024 + r * 256 + t];
  uint32_t c = 0;
#pragma unroll
  for (int r = 0; r < 4; ++r)
#pragma unroll
    for (int j = 0; j < 4; ++j) c += ((&kv[r].x)[j] >= T) ? 1u : 0u;
  scan[t] = c;
  __syncthreads();
  for (int off = 1; off < 256; off <<= 1) {
    uint32_t v = scan[t] + ((t >= off) ? scan[t - off] : 0u);
    __syncthreads();
    scan[t] = v;
    __syncthreads();
  }
  uint32_t excl = scan[t] - c;
  if (t == 255) baseSh = atomicAdd(&cnt[b], scan[255]);
  __syncthreads();
  uint32_t pos = baseSh + excl;
#pragma unroll
  for (int r = 0; r < 4; ++r)
#pragma unroll
    for (int j = 0; j < 4; ++j) {
      uint32_t k = (&kv[r].x)[j];
      if (k >= T) {
        uint32_t n = (blockIdx.x * 1024 + r * 256 + t) * 4 + j;
        if (pos < CAP)
          list[(size_t)b * CAP + pos] = ((unsigned long long)k << 32) | (uint32_t)(~n);
        pos++;
      }
    }
}

// ---------------- K3: exact rank by counting, j-split for occupancy ----------------
// Grid (i_tiles, j_chunks, B); each block: 256-item i-tile vs RJT*256-item j-chunk,
// partial counts merged via atomicAdd into zero-initialized rank[].
__global__ void rankK(const unsigned long long* __restrict__ list, const uint32_t* __restrict__ cnt,
                      uint32_t* __restrict__ rank) {
  __shared__ unsigned long long lp[256];
  int b = blockIdx.z;
  int cc = (int)min(cnt[b], (uint32_t)CAP);
  if (blockIdx.x * 256 >= cc) return;       // block-uniform
  int j0 = blockIdx.y * (256 * RJT);
  if (j0 >= cc) return;                     // block-uniform
  int i = blockIdx.x * 256 + threadIdx.x;
  unsigned long long pi = (i < cc) ? list[(size_t)b * CAP + i] : ~0ull;
  uint32_t c = 0;
#pragma unroll
  for (int tb = 0; tb < RJT; ++tb) {
    int j = j0 + tb * 256 + threadIdx.x;
    __syncthreads();
    lp[threadIdx.x] = (j < cc) ? list[(size_t)b * CAP + j] : 0ull;
    __syncthreads();
#pragma unroll 8
    for (int jj = 0; jj < 256; ++jj) c += (lp[jj] > pi) ? 1u : 0u;
  }
  if (i < cc && c) atomicAdd(&rank[(size_t)b * CAP + i], c);
}

// ---------------- K4: scatter item -> position rank; gather boxes ----------------
__global__ void scatterK(const unsigned long long* __restrict__ list,
                         const uint32_t* __restrict__ cnt, const uint32_t* __restrict__ rank,
                         const float* __restrict__ boxes, float* __restrict__ sel_score,
                         uint32_t* __restrict__ sel_idx, float* __restrict__ sel_box) {
  int b = blockIdx.y;
  int p = blockIdx.x * 256 + threadIdx.x;
  uint32_t cc = min(cnt[b], (uint32_t)CAP);
  if (p >= (int)cc) return;
  unsigned long long pk = list[(size_t)b * CAP + p];
  uint32_t r = rank[(size_t)b * CAP + p];
  if (r >= (uint32_t)KPRE) return;
  uint32_t key = (uint32_t)(pk >> 32);
  uint32_t idx = ~(uint32_t)pk;
  sel_score[b * KPRE + r] = k2f(key);
  sel_idx[b * KPRE + r] = idx;
  const float* src = boxes + ((size_t)b * N + idx) * 7;
  float* dst = sel_box + ((size_t)b * KPRE + r) * 8;
#pragma unroll
  for (int c = 0; c < 7; ++c) dst[c] = src[c];
  dst[7] = 0.f;
}

// ---------------- K5: pairwise IoU suppression bitmask (2D tiled) ----------------
__global__ void maskK(const float* __restrict__ sel_box, unsigned long long* __restrict__ mask) {
  int b = blockIdx.z;
  int bi = blockIdx.x;
  int w = blockIdx.y;
  int t = threadIdx.x;
  int i = bi * 256 + t;
  int j0 = w * 64;
  unsigned long long* dst = mask + ((size_t)b * KPRE + i) * MASKW + w;
  if (j0 + 63 <= bi * 256) { // whole tile is j <= i: no suppression bits
    *dst = 0ull;
    return;
  }
  __shared__ float jx1[64], jx2[64], jy1[64], jy2[64], ja[64];
  if (t < 64) {
    const float4* bj = (const float4*)(sel_box + ((size_t)b * KPRE + j0 + t) * 8);
    float4 lo = bj[0], hi = bj[1];
    float xj = lo.x, yj = lo.y, dxj = lo.w, dyj = hi.x;
    float hxj = __fmul_rn(dxj, 0.5f), hyj = __fmul_rn(dyj, 0.5f);
    jx1[t] = __fsub_rn(xj, hxj);
    jx2[t] = __fadd_rn(xj, hxj);
    jy1[t] = __fsub_rn(yj, hyj);
    jy2[t] = __fadd_rn(yj, hyj);
    ja[t] = __fmul_rn(dxj, dyj);
  }
  __syncthreads();
  const float4* myb = (const float4*)(sel_box + ((size_t)b * KPRE + i) * 8);
  float4 lo = myb[0], hi = myb[1];
  float x = lo.x, y = lo.y, dx = lo.w, dy = hi.x;
  float hx = __fmul_rn(dx, 0.5f), hy = __fmul_rn(dy, 0.5f);
  float x1i = __fsub_rn(x, hx), x2i = __fadd_rn(x, hx);
  float y1i = __fsub_rn(y, hy), y2i = __fadd_rn(y, hy);
  float ai = __fmul_rn(dx, dy);
  unsigned long long wacc = 0ull;
#pragma unroll 16
  for (int jj = 0; jj < 64; ++jj) {
    int j = j0 + jj;
    float xx1 = fmaxf(x1i, jx1[jj]);
    float xx2 = fminf(x2i, jx2[jj]);
    float yy1 = fmaxf(y1i, jy1[jj]);
    float yy2 = fminf(y2i, jy2[jj]);
    float ix = fmaxf(__fsub_rn(xx2, xx1), 0.0f);
    float iy = fmaxf(__fsub_rn(yy2, yy1), 0.0f);
    float inter = __fmul_rn(ix, iy);
    float uni = __fsub_rn(__fadd_rn(ai, ja[jj]), inter);
    float iou = inter / fmaxf(uni, 1e-6f);
    bool sup = (iou > NMS_THR) && (j > i);
    wacc |= ((unsigned long long)(sup ? 1u : 0u)) << jj;
  }
  *dst = wacc;
}

// ---------------- K6: greedy NMS scan, group-parallel (1 wave / batch) ----------------
__global__ void nmsK(const unsigned long long* __restrict__ mask,
                     const float* __restrict__ sel_score,
                     uint32_t* __restrict__ kept_pos, uint32_t* __restrict__ kept_cnt) {
  __shared__ unsigned long long lds[2][64][64]; // 64 KiB double buffer
  int b = blockIdx.x;
  int t = threadIdx.x; // lane 0..63; owns remv word t

  unsigned long long cand = 0ull;
  for (int k = 0; k < 64; ++k) {
    float s = sel_score[b * KPRE + k * 64 + t];
    unsigned long long bal = __ballot(s > ROI_THR);
    if (t == k) cand = bal;
  }

  const unsigned long long* mb = mask + (size_t)b * KPRE * MASKW;
  unsigned long long remv = 0ull;
  int kc = 0;

  auto prefetch = [&](int g, int buf2) {
    const char* base = (const char*)(mb + (size_t)g * 64 * MASKW);
#pragma unroll
    for (int p = 0; p < 32; ++p)
      async_lds16(base + (size_t)p * 1024 + (size_t)t * 16, &lds[buf2][p * 2][0]);
  };

  prefetch(0, 0);
  for (int g = 0; g < 64; ++g) {
    int buf = g & 1;
    asm volatile("s_waitcnt vmcnt(0)" ::: "memory"); // current buf ready
    if (g + 1 < 64) prefetch(g + 1, buf ^ 1);        // overlap next with processing

    unsigned long long cw = cand & ~remv;
    unsigned long long aw = (unsigned long long)__shfl((long long)cw, g, 64);
    if (aw) {
      unsigned long long m = lds[buf][t][g]; // who I kill within group (bits > t)
      unsigned long long K = __ballot((m & aw) != 0ull);
      unsigned long long alive = aw;
      unsigned long long rem = aw & K;
      if (rem) {
        bool deadf = ((aw >> t) & 1ull) == 0ull;
        while (rem) {
          int s = __ffsll((long long)rem) - 1;
          rem &= rem - 1ull;
          if ((alive >> s) & 1ull) { // s is final-alive here (ascending order)
            unsigned long long row_s = lds[buf][s][g]; // broadcast read
            deadf = deadf || (((row_s >> t) & 1ull) != 0ull);
            alive = __ballot(!deadf);
            rem &= alive;
          }
        }
      }
      int grp = __popcll(alive);
      if ((alive >> t) & 1ull) {
        int rk = __popcll(alive & ((1ull << t) - 1ull));
        if (kc + rk < KPOST) kept_pos[b * KPOST + kc + rk] = g * 64 + t;
      }
      unsigned long long acc = 0ull, a2 = alive;
      while (a2) {
        int s2 = __ffsll((long long)a2) - 1;
        a2 &= a2 - 1ull;
        acc |= lds[buf][s2][t];
      }
      remv |= acc;
      kc += grp;
      if (kc >= KPOST) break;
    }
  }
  asm volatile("s_waitcnt vmcnt(0)" ::: "memory"); // drain in-flight prefetch
  if (t == 0) kept_cnt[b] = (uint32_t)min(kc, KPOST);
}

// ---------------- K7: emit outputs ----------------
__global__ void outK(const float* __restrict__ cls,
                     const float* __restrict__ sel_score, const uint32_t* __restrict__ sel_idx,
                     const float* __restrict__ sel_box,
                     const uint32_t* __restrict__ kept_pos, const uint32_t* __restrict__ kept_cnt,
                     float* __restrict__ out) {
  int b = blockIdx.y;
  int s = blockIdx.x * blockDim.x + threadIdx.x;
  if (s >= KPOST) return;
  float* oS = out;                             // (B, KPOST)
  float* oB = out + B * KPOST;                 // (B, KPOST, 7)
  float* oL = out + B * KPOST + B * KPOST * 7; // (B, KPOST)
  uint32_t kcnt = kept_cnt[b];
  if (s < (int)kcnt) {
    uint32_t pos = kept_pos[b * KPOST + s];
    oS[b * KPOST + s] = sel_score[b * KPRE + pos];
    const float* box = sel_box + ((size_t)b * KPRE + pos) * 8;
    float* dst = oB + ((size_t)b * KPOST + s) * 7;
#pragma unroll
    for (int c = 0; c < 7; ++c) dst[c] = box[c];
    uint32_t idx = sel_idx[b * KPRE + pos];
    const float* p = cls + ((size_t)b * N + idx) * C;
    float bestv = sigm(p[0]);
    int bestc = 0;
#pragma unroll
    for (int c = 1; c < C; ++c) {
      float v = sigm(p[c]);
      if (v > bestv) { bestv = v; bestc = c; }
    }
    oL[b * KPOST + s] = (float)bestc;
  } else {
    oS[b * KPOST + s] = 0.0f;
    float* dst = oB + ((size_t)b * KPOST + s) * 7;
#pragma unroll
    for (int c = 0; c < 7; ++c) dst[c] = 0.0f;
    oL[b * KPOST + s] = -1.0f;
  }
}

__global__ void sentinelK(float* out, int n) {
  int i = blockIdx.x * blockDim.x + threadIdx.x;
  if (i < n) out[i] = 1337.0f;
}

extern "C" void kernel_launch(void* const* d_in, const int* in_sizes, int n_in,
                              void* d_out, int out_size, void* d_ws, size_t ws_size,
                              hipStream_t stream) {
  const float* cls = (const float*)d_in[0];
  const float* boxes = (const float*)d_in[1];
  float* out = (float*)d_out;

  char* ws = (char*)d_ws;
  size_t off = 0;
  auto alloc = [&](size_t bytes) -> void* {
    void* p = ws + off;
    off = (off + bytes + 255) & ~(size_t)255;
    return p;
  };
  unsigned long long* mask = (unsigned long long*)alloc((size_t)B * KPRE * MASKW * 8); // 8 MB
  unsigned long long* list = (unsigned long long*)alloc((size_t)B * CAP * 8);
  uint32_t* keys = (uint32_t*)alloc((size_t)B * N * 4);
  float* sel_box = (float*)alloc((size_t)B * KPRE * 8 * 4);
  float* sel_score = (float*)alloc((size_t)B * KPRE * 4);
  uint32_t* sel_idx = (uint32_t*)alloc((size_t)B * KPRE * 4);
  uint32_t* kept_pos = (uint32_t*)alloc((size_t)B * KPOST * 4);
  uint32_t* kept_cnt = (uint32_t*)alloc(B * 4); // NOT aliased: written by nmsK after maskK

  // Aliases into the mask region — all dead before maskK writes mask:
  //   hist0/1 (B*256 u32 each), cnt (B u32): zeroed by memset, read before maskK.
  //   rank (B*CAP u32): zeroed by memset, atomicAdd'd by rankK, read by scatterK.
  uint32_t* hist0 = (uint32_t*)mask;
  uint32_t* hist1 = hist0 + B * 256;
  uint32_t* cnt = hist1 + B * 256;
  uint32_t* rank = (uint32_t*)((char*)mask + 16384);
  size_t zbytes = 16384 + (size_t)B * CAP * 4; // hists + cnt + rank

  if (off > ws_size) {
    sentinelK<<<dim3((out_size + 255) / 256), 256, 0, stream>>>(out, out_size);
    return;
  }

  hipMemsetAsync(mask, 0, zbytes, stream);
  scoreK<<<dim3(N / 256, B), 256, 0, stream>>>(cls, keys, hist0);
  histP1K<<<dim3(N / 2048, B), 256, 0, stream>>>(keys, hist0, hist1);
  compactK<<<dim3(N / 4096, B), 256, 0, stream>>>(keys, hist0, hist1, list, cnt);
  rankK<<<dim3(CAP / 256, CAP / (256 * RJT), B), 256, 0, stream>>>(list, cnt, rank);
  scatterK<<<dim3(CAP / 256, B), 256, 0, stream>>>(list, cnt, rank, boxes, sel_score, sel_idx,
                                                   sel_box);
  maskK<<<dim3(16, 64, B), 256, 0, stream>>>(sel_box, mask);
  nmsK<<<B, 64, 0, stream>>>(mask, sel_score, kept_pos, kept_cnt);
  outK<<<dim3((KPOST + 255) / 256, B), 256, 0, stream>>>(cls, sel_score, sel_idx, sel_box,
                                                         kept_pos, kept_cnt, out);
}

// Round 8
// 153.980 us; speedup vs baseline: 3.4897x; 1.0799x over previous
//
#include <hip/hip_runtime.h>
#include <stdint.h>

constexpr int B = 4;
constexpr int N = 262144;
constexpr int C = 10;
constexpr int KPRE = 4096;
constexpr int KPOST = 500;
constexpr float ROI_THR = 0.1f;
constexpr float NMS_THR = 0.01f;
constexpr int CAP = 8192;        // compaction capacity (>= KPRE + boundary-bin ties)
constexpr int MASKW = KPRE / 64; // 64 u64 words per mask row
constexpr int RJT = 2;           // j-tiles per rankK block

__device__ __forceinline__ uint32_t f2k(float f) {
  uint32_t u = __float_as_uint(f);
  return (u & 0x80000000u) ? ~u : (u | 0x80000000u);
}
__device__ __forceinline__ float k2f(uint32_t k) {
  uint32_t u = (k & 0x80000000u) ? (k ^ 0x80000000u) : ~k;
  return __uint_as_float(u);
}
__device__ __forceinline__ float sigm(float x) { return 1.0f / (1.0f + expf(-x)); }

__device__ __forceinline__ void async_lds16(const void* g, void* l) {
  __builtin_amdgcn_global_load_lds((const __attribute__((address_space(1))) void*)g,
                                   (__attribute__((address_space(3))) void*)l, 16, 0, 0);
}

// Suffix-select on a 256-bin histogram: returns (bin, residual rank). blockDim==256.
__device__ __forceinline__ uint2 select256(const uint32_t* __restrict__ h, uint32_t R,
                                           uint32_t* s, uint32_t* o2) {
  int t = threadIdx.x;
  s[t] = h[t];
  __syncthreads();
  for (int off = 1; off < 256; off <<= 1) {
    uint32_t v = s[t] + ((t + off < 256) ? s[t + off] : 0u);
    __syncthreads();
    s[t] = v;
    __syncthreads();
  }
  uint32_t suf = s[t];
  uint32_t sufn = (t < 255) ? s[t + 1] : 0u;
  if (suf >= R && R > sufn) {
    o2[0] = (uint32_t)t;
    o2[1] = R - sufn;
  }
  __syncthreads();
  uint2 r;
  r.x = o2[0];
  r.y = o2[1];
  __syncthreads(); // protect scratch reuse
  return r;
}

// ---------------- K0: keys + pass-0 histogram. max commutes with monotone sigmoid:
// max_i RN(sigm(l_i)) == RN(sigm(max_i l_i)) exactly -> one sigmoid per item. ----------------
__global__ void scoreK(const float* __restrict__ cls, uint32_t* __restrict__ keys,
                       uint32_t* __restrict__ hist0) {
  __shared__ float ls[2560]; // 256 items x 10 classes
  __shared__ uint32_t h[256];
  int b = blockIdx.y;
  int t = threadIdx.x;
  h[t] = 0;
  size_t base = ((size_t)b * N + (size_t)blockIdx.x * 256) * C;
  const float2* g2 = (const float2*)(cls + base);
  float2* l2 = (float2*)ls;
#pragma unroll
  for (int r = 0; r < 5; ++r) l2[r * 256 + t] = g2[r * 256 + t]; // coalesced 512B/wave
  __syncthreads();
  const float* mine = ls + t * 10;
  float m = mine[0];
#pragma unroll
  for (int c = 1; c < C; ++c) m = fmaxf(m, mine[c]); // max logit
  float p = sigm(m);                                  // == max prob (monotone)
  float sc = (p > ROI_THR) ? p : -1.0f;
  uint32_t k = f2k(sc);
  keys[(size_t)b * N + blockIdx.x * 256 + t] = k;
  atomicAdd(&h[k >> 24], 1u);
  __syncthreads();
  if (h[t]) atomicAdd(&hist0[b * 256 + t], h[t]);
}

// ---------------- K1: byte-1 histogram among items matching pass-0 byte ----------------
__global__ void histP1K(const uint32_t* __restrict__ keys, const uint32_t* __restrict__ hist0,
                        uint32_t* __restrict__ hist1) {
  __shared__ uint32_t s[256];
  __shared__ uint32_t o2[2];
  __shared__ uint32_t h[256];
  int b = blockIdx.y;
  int t = threadIdx.x;
  uint2 s0 = select256(hist0 + b * 256, (uint32_t)KPRE, s, o2);
  h[t] = 0;
  __syncthreads();
  uint32_t pref = s0.x;
  const uint4* kb4 = (const uint4*)(keys + (size_t)b * N);
#pragma unroll
  for (int r = 0; r < 2; ++r) {
    uint4 kv = kb4[blockIdx.x * 512 + r * 256 + t];
#pragma unroll
    for (int j = 0; j < 4; ++j) {
      uint32_t k = (&kv.x)[j];
      if ((k >> 24) == pref) atomicAdd(&h[(k >> 16) & 255u], 1u);
    }
  }
  __syncthreads();
  if (h[t]) atomicAdd(&hist1[b * 256 + t], h[t]);
}

// ---------------- K2: 16-bit threshold; block-aggregated stream compaction ----------------
__global__ void compactK(const uint32_t* __restrict__ keys, const uint32_t* __restrict__ hist0,
                         const uint32_t* __restrict__ hist1, unsigned long long* __restrict__ list,
                         uint32_t* __restrict__ cnt) {
  __shared__ uint32_t s[256];
  __shared__ uint32_t o2[2];
  __shared__ uint32_t scan[256];
  __shared__ uint32_t baseSh;
  int b = blockIdx.y;
  int t = threadIdx.x;
  uint2 s0 = select256(hist0 + b * 256, (uint32_t)KPRE, s, o2);
  uint2 s1 = select256(hist1 + b * 256, s0.y, s, o2);
  uint32_t T = ((s0.x << 8) | s1.x) << 16;
  const uint4* kb4 = (const uint4*)(keys + (size_t)b * N);
  uint4 kv[4];
#pragma unroll
  for (int r = 0; r < 4; ++r) kv[r] = kb4[blockIdx.x * 1024 + r * 256 + t];
  uint32_t c = 0;
#pragma unroll
  for (int r = 0; r < 4; ++r)
#pragma unroll
    for (int j = 0; j < 4; ++j) c += ((&kv[r].x)[j] >= T) ? 1u : 0u;
  scan[t] = c;
  __syncthreads();
  for (int off = 1; off < 256; off <<= 1) {
    uint32_t v = scan[t] + ((t >= off) ? scan[t - off] : 0u);
    __syncthreads();
    scan[t] = v;
    __syncthreads();
  }
  uint32_t excl = scan[t] - c;
  if (t == 255) baseSh = atomicAdd(&cnt[b], scan[255]);
  __syncthreads();
  uint32_t pos = baseSh + excl;
#pragma unroll
  for (int r = 0; r < 4; ++r)
#pragma unroll
    for (int j = 0; j < 4; ++j) {
      uint32_t k = (&kv[r].x)[j];
      if (k >= T) {
        uint32_t n = (blockIdx.x * 1024 + r * 256 + t) * 4 + j;
        if (pos < CAP)
          list[(size_t)b * CAP + pos] = ((unsigned long long)k << 32) | (uint32_t)(~n);
        pos++;
      }
    }
}

// ---------------- K3: exact rank by counting, j-split for occupancy ----------------
__global__ void rankK(const unsigned long long* __restrict__ list, const uint32_t* __restrict__ cnt,
                      uint32_t* __restrict__ rank) {
  __shared__ unsigned long long lp[256];
  int b = blockIdx.z;
  int cc = (int)min(cnt[b], (uint32_t)CAP);
  if (blockIdx.x * 256 >= cc) return; // block-uniform
  int j0 = blockIdx.y * (256 * RJT);
  if (j0 >= cc) return; // block-uniform
  int i = blockIdx.x * 256 + threadIdx.x;
  unsigned long long pi = (i < cc) ? list[(size_t)b * CAP + i] : ~0ull;
  uint32_t c = 0;
#pragma unroll
  for (int tb = 0; tb < RJT; ++tb) {
    int j = j0 + tb * 256 + threadIdx.x;
    __syncthreads();
    lp[threadIdx.x] = (j < cc) ? list[(size_t)b * CAP + j] : 0ull;
    __syncthreads();
#pragma unroll 8
    for (int jj = 0; jj < 256; ++jj) c += (lp[jj] > pi) ? 1u : 0u;
  }
  if (i < cc && c) atomicAdd(&rank[(size_t)b * CAP + i], c);
}

// ---------------- K4: scatter item -> position rank; gather boxes ----------------
__global__ void scatterK(const unsigned long long* __restrict__ list,
                         const uint32_t* __restrict__ cnt, const uint32_t* __restrict__ rank,
                         const float* __restrict__ boxes, float* __restrict__ sel_score,
                         uint32_t* __restrict__ sel_idx, float* __restrict__ sel_box) {
  int b = blockIdx.y;
  int p = blockIdx.x * 256 + threadIdx.x;
  uint32_t cc = min(cnt[b], (uint32_t)CAP);
  if (p >= (int)cc) return;
  unsigned long long pk = list[(size_t)b * CAP + p];
  uint32_t r = rank[(size_t)b * CAP + p];
  if (r >= (uint32_t)KPRE) return;
  uint32_t key = (uint32_t)(pk >> 32);
  uint32_t idx = ~(uint32_t)pk;
  sel_score[b * KPRE + r] = k2f(key);
  sel_idx[b * KPRE + r] = idx;
  const float* src = boxes + ((size_t)b * N + idx) * 7;
  float* dst = sel_box + ((size_t)b * KPRE + r) * 8;
#pragma unroll
  for (int c = 0; c < 7; ++c) dst[c] = src[c];
  dst[7] = 0.f;
}

// ---------------- K5: pairwise IoU suppression bitmask (2D tiled, division-free) ----------------
// Decision RN(inter/den) > 0.01 resolved by comparing inter vs q0=RN(0.01*den) with a
// conservative relative band (1e-5 >> f32 rounding); inside the band (wave-uniform, ~never)
// fall back to the exact IEEE division. Bit-identical to the reference decision.
__global__ void maskK(const float* __restrict__ sel_box, unsigned long long* __restrict__ mask) {
  int b = blockIdx.z;
  int bi = blockIdx.x;
  int w = blockIdx.y;
  int t = threadIdx.x;
  int i = bi * 256 + t;
  int j0 = w * 64;
  unsigned long long* dst = mask + ((size_t)b * KPRE + i) * MASKW + w;
  if (j0 + 63 <= bi * 256) { // whole tile is j <= i: no suppression bits
    *dst = 0ull;
    return;
  }
  __shared__ float4 jv[64]; // {x1, x2, y1, y2}
  __shared__ float ja[64];
  if (t < 64) {
    const float4* bj = (const float4*)(sel_box + ((size_t)b * KPRE + j0 + t) * 8);
    float4 lo = bj[0], hi = bj[1];
    float xj = lo.x, yj = lo.y, dxj = lo.w, dyj = hi.x;
    float hxj = __fmul_rn(dxj, 0.5f), hyj = __fmul_rn(dyj, 0.5f);
    float4 v;
    v.x = __fsub_rn(xj, hxj);
    v.y = __fadd_rn(xj, hxj);
    v.z = __fsub_rn(yj, hyj);
    v.w = __fadd_rn(yj, hyj);
    jv[t] = v;
    ja[t] = __fmul_rn(dxj, dyj);
  }
  __syncthreads();
  const float4* myb = (const float4*)(sel_box + ((size_t)b * KPRE + i) * 8);
  float4 lo = myb[0], hi = myb[1];
  float x = lo.x, y = lo.y, dx = lo.w, dy = hi.x;
  float hx = __fmul_rn(dx, 0.5f), hy = __fmul_rn(dy, 0.5f);
  float x1i = __fsub_rn(x, hx), x2i = __fadd_rn(x, hx);
  float y1i = __fsub_rn(y, hy), y2i = __fadd_rn(y, hy);
  float ai = __fmul_rn(dx, dy);
  unsigned long long wacc = 0ull;
#pragma unroll 16
  for (int jj = 0; jj < 64; ++jj) {
    int j = j0 + jj;
    float4 v = jv[jj];
    float aj = ja[jj];
    float xx1 = fmaxf(x1i, v.x);
    float xx2 = fminf(x2i, v.y);
    float yy1 = fmaxf(y1i, v.z);
    float yy2 = fminf(y2i, v.w);
    float ix = fmaxf(__fsub_rn(xx2, xx1), 0.0f);
    float iy = fmaxf(__fsub_rn(yy2, yy1), 0.0f);
    float inter = __fmul_rn(ix, iy);
    float den = fmaxf(__fsub_rn(__fadd_rn(ai, aj), inter), 1e-6f);
    float q0 = __fmul_rn(NMS_THR, den);
    float d = __fsub_rn(inter, q0);
    bool sup = d > 0.0f;
    if (__builtin_expect(__any(fabsf(d) <= q0 * 1e-5f), 0)) {
      sup = (inter / den) > NMS_THR; // exact IEEE path, wave-uniform & rare
    }
    sup = sup && (j > i);
    wacc |= ((unsigned long long)(sup ? 1u : 0u)) << jj;
  }
  *dst = wacc;
}

// ---------------- K6: greedy NMS scan, group-parallel (1 wave / batch) ----------------
__global__ void nmsK(const unsigned long long* __restrict__ mask,
                     const float* __restrict__ sel_score,
                     uint32_t* __restrict__ kept_pos, uint32_t* __restrict__ kept_cnt) {
  __shared__ unsigned long long lds[2][64][64]; // 64 KiB double buffer
  int b = blockIdx.x;
  int t = threadIdx.x; // lane 0..63; owns remv word t

  unsigned long long cand = 0ull;
  for (int k = 0; k < 64; ++k) {
    float s = sel_score[b * KPRE + k * 64 + t];
    unsigned long long bal = __ballot(s > ROI_THR);
    if (t == k) cand = bal;
  }

  const unsigned long long* mb = mask + (size_t)b * KPRE * MASKW;
  unsigned long long remv = 0ull;
  int kc = 0;

  auto prefetch = [&](int g, int buf2) {
    const char* base = (const char*)(mb + (size_t)g * 64 * MASKW);
#pragma unroll
    for (int p = 0; p < 32; ++p)
      async_lds16(base + (size_t)p * 1024 + (size_t)t * 16, &lds[buf2][p * 2][0]);
  };

  prefetch(0, 0);
  for (int g = 0; g < 64; ++g) {
    int buf = g & 1;
    asm volatile("s_waitcnt vmcnt(0)" ::: "memory"); // current buf ready
    if (g + 1 < 64) prefetch(g + 1, buf ^ 1);        // overlap next with processing

    unsigned long long cw = cand & ~remv;
    unsigned long long aw = (unsigned long long)__shfl((long long)cw, g, 64);
    if (aw) {
      unsigned long long m = lds[buf][t][g]; // who I kill within group (bits > t)
      unsigned long long K = __ballot((m & aw) != 0ull);
      unsigned long long alive = aw;
      unsigned long long rem = aw & K;
      if (rem) {
        bool deadf = ((aw >> t) & 1ull) == 0ull;
        while (rem) {
          int s = __ffsll((long long)rem) - 1;
          rem &= rem - 1ull;
          if ((alive >> s) & 1ull) { // s is final-alive here (ascending order)
            unsigned long long row_s = lds[buf][s][g]; // broadcast read
            deadf = deadf || (((row_s >> t) & 1ull) != 0ull);
            alive = __ballot(!deadf);
            rem &= alive;
          }
        }
      }
      int grp = __popcll(alive);
      if ((alive >> t) & 1ull) {
        int rk = __popcll(alive & ((1ull << t) - 1ull));
        if (kc + rk < KPOST) kept_pos[b * KPOST + kc + rk] = g * 64 + t;
      }
      unsigned long long acc = 0ull, a2 = alive;
      while (a2) {
        int s2 = __ffsll((long long)a2) - 1;
        a2 &= a2 - 1ull;
        acc |= lds[buf][s2][t];
      }
      remv |= acc;
      kc += grp;
      if (kc >= KPOST) break;
    }
  }
  asm volatile("s_waitcnt vmcnt(0)" ::: "memory"); // drain in-flight prefetch
  if (t == 0) kept_cnt[b] = (uint32_t)min(kc, KPOST);
}

// ---------------- K7: emit outputs ----------------
__global__ void outK(const float* __restrict__ cls,
                     const float* __restrict__ sel_score, const uint32_t* __restrict__ sel_idx,
                     const float* __restrict__ sel_box,
                     const uint32_t* __restrict__ kept_pos, const uint32_t* __restrict__ kept_cnt,
                     float* __restrict__ out) {
  int b = blockIdx.y;
  int s = blockIdx.x * blockDim.x + threadIdx.x;
  if (s >= KPOST) return;
  float* oS = out;                             // (B, KPOST)
  float* oB = out + B * KPOST;                 // (B, KPOST, 7)
  float* oL = out + B * KPOST + B * KPOST * 7; // (B, KPOST)
  uint32_t kcnt = kept_cnt[b];
  if (s < (int)kcnt) {
    uint32_t pos = kept_pos[b * KPOST + s];
    oS[b * KPOST + s] = sel_score[b * KPRE + pos];
    const float* box = sel_box + ((size_t)b * KPRE + pos) * 8;
    float* dst = oB + ((size_t)b * KPOST + s) * 7;
#pragma unroll
    for (int c = 0; c < 7; ++c) dst[c] = box[c];
    uint32_t idx = sel_idx[b * KPRE + pos];
    const float* p = cls + ((size_t)b * N + idx) * C;
    float bestv = sigm(p[0]);
    int bestc = 0;
#pragma unroll
    for (int c = 1; c < C; ++c) {
      float v = sigm(p[c]);
      if (v > bestv) { bestv = v; bestc = c; }
    }
    oL[b * KPOST + s] = (float)bestc;
  } else {
    oS[b * KPOST + s] = 0.0f;
    float* dst = oB + ((size_t)b * KPOST + s) * 7;
#pragma unroll
    for (int c = 0; c < 7; ++c) dst[c] = 0.0f;
    oL[b * KPOST + s] = -1.0f;
  }
}

__global__ void sentinelK(float* out, int n) {
  int i = blockIdx.x * blockDim.x + threadIdx.x;
  if (i < n) out[i] = 1337.0f;
}

extern "C" void kernel_launch(void* const* d_in, const int* in_sizes, int n_in,
                              void* d_out, int out_size, void* d_ws, size_t ws_size,
                              hipStream_t stream) {
  const float* cls = (const float*)d_in[0];
  const float* boxes = (const float*)d_in[1];
  float* out = (float*)d_out;

  char* ws = (char*)d_ws;
  size_t off = 0;
  auto alloc = [&](size_t bytes) -> void* {
    void* p = ws + off;
    off = (off + bytes + 255) & ~(size_t)255;
    return p;
  };
  unsigned long long* mask = (unsigned long long*)alloc((size_t)B * KPRE * MASKW * 8); // 8 MB
  unsigned long long* list = (unsigned long long*)alloc((size_t)B * CAP * 8);
  uint32_t* keys = (uint32_t*)alloc((size_t)B * N * 4);
  float* sel_box = (float*)alloc((size_t)B * KPRE * 8 * 4);
  float* sel_score = (float*)alloc((size_t)B * KPRE * 4);
  uint32_t* sel_idx = (uint32_t*)alloc((size_t)B * KPRE * 4);
  uint32_t* kept_pos = (uint32_t*)alloc((size_t)B * KPOST * 4);
  uint32_t* kept_cnt = (uint32_t*)alloc(B * 4); // NOT aliased: written by nmsK after maskK

  // Aliases into the mask region — all dead before maskK writes mask:
  //   hist0/1 (B*256 u32 each), cnt (B u32): zeroed by memset, read before maskK.
  //   rank (B*CAP u32): zeroed by memset, atomicAdd'd by rankK, read by scatterK.
  uint32_t* hist0 = (uint32_t*)mask;
  uint32_t* hist1 = hist0 + B * 256;
  uint32_t* cnt = hist1 + B * 256;
  uint32_t* rank = (uint32_t*)((char*)mask + 16384);
  size_t zbytes = 16384 + (size_t)B * CAP * 4; // hists + cnt + rank

  if (off > ws_size) {
    sentinelK<<<dim3((out_size + 255) / 256), 256, 0, stream>>>(out, out_size);
    return;
  }

  hipMemsetAsync(mask, 0, zbytes, stream);
  scoreK<<<dim3(N / 256, B), 256, 0, stream>>>(cls, keys, hist0);
  histP1K<<<dim3(N / 2048, B), 256, 0, stream>>>(keys, hist0, hist1);
  compactK<<<dim3(N / 4096, B), 256, 0, stream>>>(keys, hist0, hist1, list, cnt);
  rankK<<<dim3(CAP / 256, CAP / (256 * RJT), B), 256, 0, stream>>>(list, cnt, rank);
  scatterK<<<dim3(CAP / 256, B), 256, 0, stream>>>(list, cnt, rank, boxes, sel_score, sel_idx,
                                                   sel_box);
  maskK<<<dim3(16, 64, B), 256, 0, stream>>>(sel_box, mask);
  nmsK<<<B, 64, 0, stream>>>(mask, sel_score, kept_pos, kept_cnt);
  outK<<<dim3((KPOST + 255) / 256, B), 256, 0, stream>>>(cls, sel_score, sel_idx, sel_box,
                                                         kept_pos, kept_cnt, out);
}